// Round 19
// baseline (612.579 us; speedup 1.0000x reference)
//
#include <hip/hip_runtime.h>
#include <hip/hip_bf16.h>

#define B_ 4
#define N_ 2048
#define E_ 512
#define EMB_ 1024
#define H_ 8
#define D_ 128
#define KNN_ 16

typedef short short8_t __attribute__((ext_vector_type(8)));
typedef short short4_t __attribute__((ext_vector_type(4)));
typedef float float2_t __attribute__((ext_vector_type(2)));
typedef float float4_t __attribute__((ext_vector_type(4)));
typedef float float16_t __attribute__((ext_vector_type(16)));
typedef unsigned int uint2_t __attribute__((ext_vector_type(2)));
typedef unsigned int uint4_t __attribute__((ext_vector_type(4)));

__device__ __forceinline__ short f2bf(float f) {
  unsigned u = __float_as_uint(f);
  unsigned r = u + 0x7fffu + ((u >> 16) & 1u);   // RNE to bf16
  return (short)(r >> 16);
}

__device__ __forceinline__ unsigned pk2bf(float a, float b) {
  float2 f; f.x = a; f.y = b;
  __hip_bfloat162 h = __float22bfloat162_rn(f);
  return *(unsigned*)&h;
}

__device__ __forceinline__ float bf2f(short s) {
  return __uint_as_float(((unsigned)(unsigned short)s) << 16);
}

__device__ __forceinline__ float fexp2(float x) {
  return __builtin_amdgcn_exp2f(x);
}

// async global->LDS, 16 B per lane (per-lane global addr, wave-linear LDS dest)
__device__ __forceinline__ void gload16(const short* g, short* l) {
  __builtin_amdgcn_global_load_lds(
      (const __attribute__((address_space(1))) void*)g,
      (__attribute__((address_space(3))) void*)l, 16, 0, 0);
}

// exact 16-value pairwise tree, bit-identical to the r7-verified k_sqnp_fin
__device__ __forceinline__ float tree16(const float* __restrict__ bs) {
  float t1[8], t2[4];
#pragma unroll
  for (int l = 0; l < 8; l++) t1[l] = __fadd_rn(bs[2 * l], bs[2 * l + 1]);
#pragma unroll
  for (int l = 0; l < 4; l++) t2[l] = __fadd_rn(t1[2 * l], t1[2 * l + 1]);
  return __fadd_rn(__fadd_rn(t2[0], t2[1]), __fadd_rn(t2[2], t2[3]));
}

// ---------------------------------------------------------------------------
// K1: Gram j-half split + fused sqnp_part (verified r16/r18). Bit-exact.
// ---------------------------------------------------------------------------
__global__ __launch_bounds__(64) void k_gram_sqnp(const float* __restrict__ x,
                                                  float* __restrict__ g,
                                                  float* __restrict__ part) {
  const int bx = blockIdx.x;
  const int b = blockIdx.y;
  if (bx >= 272) {                       // ---- sqnp_part path
    const int idx = (bx - 272) * 64 + threadIdx.x;   // 0..8191
    const int e = idx & (E_ - 1), blk = idx >> 9;
    const float* p = x + (size_t)b * N_ * E_ + (size_t)blk * 128 * E_ + e;
    float lane[16];
#pragma unroll
    for (int l = 0; l < 16; l++) {
      float pr[8];
#pragma unroll
      for (int j = 0; j < 8; j++) {
        float v = p[(size_t)(j * 16 + l) * E_];
        pr[j] = __fmul_rn(v, v);
      }
      float s01 = __fadd_rn(pr[0], pr[1]);
      float s23 = __fadd_rn(pr[2], pr[3]);
      float s45 = __fadd_rn(pr[4], pr[5]);
      float s67 = __fadd_rn(pr[6], pr[7]);
      lane[l] = __fadd_rn(__fadd_rn(s01, s23), __fadd_rn(s45, s67));
    }
    float bb[8];
#pragma unroll
    for (int l = 0; l < 8; l++) bb[l] = __fadd_rn(lane[l], lane[l + 8]);
    float cc[4];
#pragma unroll
    for (int l = 0; l < 4; l++) cc[l] = __fadd_rn(bb[l], bb[l + 4]);
    part[((size_t)b * E_ + e) * 16 + blk] =
        __fadd_rn(__fadd_rn(cc[0], cc[1]), __fadd_rn(cc[2], cc[3]));
    return;
  }
  // ---- gram path (verified r13/r16): 32i x 16j half-pair per wave
  __shared__ __align__(16) float Xs[2][32][68];  // [0..31]=i, [32..47]=j half
  int p = bx >> 1;
  const int jh = bx & 1;
  int ti = 0;
  while (p >= 16 - ti) { p -= 16 - ti; ti++; }
  const int tj = ti + p;
  const int i0 = ti * 32, j0 = tj * 32 + jh * 16;
  const int lane = threadIdx.x;
  const int li = lane & 7, lj = lane >> 3;     // compute: i-quad, j-pair
  const int cq = lane & 7, rn = lane >> 3;     // i-staging: ch-quad, n-row
  const int qj = lane & 3, rj = lane >> 2;     // j-staging: ch-quad, n-row
  const float* xb = x + (size_t)b * N_ * E_;

  float acc[4][2];
#pragma unroll
  for (int u = 0; u < 4; u++) { acc[u][0] = 0.f; acc[u][1] = 0.f; }

  float4_t gi[4], gj[2];
#pragma unroll
  for (int ps = 0; ps < 4; ps++) {       // chunk 0 i-part -> regs
    const int n = ps * 8 + rn;
    gi[ps] = *(const float4_t*)(xb + (size_t)n * E_ + i0 + cq * 4);
  }
#pragma unroll
  for (int s = 0; s < 2; s++) {          // chunk 0 j-part -> regs
    const int n = s * 16 + rj;
    gj[s] = *(const float4_t*)(xb + (size_t)n * E_ + j0 + qj * 4);
  }
#pragma unroll
  for (int ps = 0; ps < 4; ps++) {       // regs -> buf0 (i)
    const int nn = ps * 8 + rn;
    *(float4_t*)&Xs[0][nn][(cq * 4) ^ ((nn & 7) << 2)] = gi[ps];
  }
#pragma unroll
  for (int s = 0; s < 2; s++) {          // regs -> buf0 (j)
    const int nn = s * 16 + rj;
    *(float4_t*)&Xs[0][nn][32 + ((qj * 4) ^ ((nn & 3) << 2))] = gj[s];
  }

  for (int c = 0; c < 64; c++) {
    const int buf = c & 1;
    if (c < 63) {                        // issue next chunk's global loads
      const int nb = (c + 1) * 32;
#pragma unroll
      for (int ps = 0; ps < 4; ps++) {
        const int n = nb + ps * 8 + rn;
        gi[ps] = *(const float4_t*)(xb + (size_t)n * E_ + i0 + cq * 4);
      }
#pragma unroll
      for (int s = 0; s < 2; s++) {
        const int n = nb + s * 16 + rj;
        gj[s] = *(const float4_t*)(xb + (size_t)n * E_ + j0 + qj * 4);
      }
    }
#pragma unroll
    for (int nn = 0; nn < 32; nn++) {    // compute 32 nn (exact chain order)
      const float4_t va = *(const float4_t*)
          &Xs[buf][nn][(li * 4) ^ ((nn & 7) << 2)];
      const float2_t vb = *(const float2_t*)
          &Xs[buf][nn][32 + (((lj >> 1) * 4) ^ ((nn & 3) << 2)) + (lj & 1) * 2];
#pragma unroll
      for (int u = 0; u < 4; u++) {
        acc[u][0] = __fadd_rn(acc[u][0], __fmul_rn(va[u], vb[0]));
        acc[u][1] = __fadd_rn(acc[u][1], __fmul_rn(va[u], vb[1]));
      }
    }
    if (c < 63) {                        // regs -> other buffer (no barrier:
#pragma unroll
      for (int ps = 0; ps < 4; ps++) {   //  single wave, disjoint buffer)
        const int nn = ps * 8 + rn;
        *(float4_t*)&Xs[buf ^ 1][nn][(cq * 4) ^ ((nn & 7) << 2)] = gi[ps];
      }
#pragma unroll
      for (int s = 0; s < 2; s++) {
        const int nn = s * 16 + rj;
        *(float4_t*)&Xs[buf ^ 1][nn][32 + ((qj * 4) ^ ((nn & 3) << 2))] = gj[s];
      }
    }
  }
  float* gb = g + (size_t)b * E_ * E_;
#pragma unroll
  for (int u = 0; u < 4; u++) {
#pragma unroll
    for (int v = 0; v < 2; v++) {
      const int i = i0 + li * 4 + u, j = j0 + lj * 2 + v;
      gb[(size_t)i * E_ + j] = acc[u][v];
      if (ti != tj) gb[(size_t)j * E_ + i] = acc[u][v];
    }
  }
}

// ---------------------------------------------------------------------------
// K2: top-16 with inline sq tree (verified r16), single-wave butterfly.
// ---------------------------------------------------------------------------
__global__ __launch_bounds__(64) void k_topk(const float* __restrict__ part,
                                             const float* __restrict__ g,
                                             int* __restrict__ idxout) {
  const int bi = blockIdx.x;            // b*E + i
  const int b = bi >> 9, i = bi & (E_ - 1);
  const int lane = threadIdx.x;
  const float* gb = g + ((size_t)b * E_ + i) * E_;
  const float* pb = part + ((size_t)b << 9) * 16;
  const float sqi = tree16(pb + (size_t)i * 16);
  const int base = lane * 8;
  float v[8];
#pragma unroll
  for (int u = 0; u < 8; u++) {
    const float sqj = tree16(pb + (size_t)(base + u) * 16);
    v[u] = __fsub_rn(__fadd_rn(sqi, sqj), __fmul_rn(2.0f, gb[base + u]));
  }
  for (int t = 0; t < KNN_; t++) {
    float best = 3.0e38f; int bidx = E_;
#pragma unroll
    for (int u = 0; u < 8; u++) {
      if (v[u] < best) { best = v[u]; bidx = base + u; }
    }
#pragma unroll
    for (int off = 1; off < 64; off <<= 1) {
      float ov = __shfl_xor(best, off);
      int oi = __shfl_xor(bidx, off);
      if (ov < best || (ov == best && oi < bidx)) { best = ov; bidx = oi; }
    }
    if (lane == 0) idxout[(size_t)bi * KNN_ + t] = bidx;
#pragma unroll
    for (int u = 0; u < 8; u++) {
      if (bidx == base + u) v[u] = 3.0e38f;
    }
  }
}

// ---------------------------------------------------------------------------
// K3: x_knn mean + interleaved q + fused bf16 Xq write (verified r14).
// ---------------------------------------------------------------------------
__global__ __launch_bounds__(256) void k_knnmean(const float* __restrict__ x,
                                                 const int* __restrict__ idx,
                                                 float* __restrict__ out,
                                                 short* __restrict__ Xq) {
  const int n = blockIdx.x, b = blockIdx.y;
  const int tid = threadIdx.x;
  __shared__ float xrow[E_];
  const float* xr = x + ((size_t)b * N_ + n) * E_;
  for (int i = tid; i < E_; i += 256) xrow[i] = xr[i];
  __syncthreads();
  float* orow = out + ((size_t)b * (2 * N_) + n) * EMB_;
  unsigned* qrow = (unsigned*)(Xq + ((size_t)b * N_ + n) * EMB_);
  for (int i = tid; i < E_; i += 256) {
    const int* id = idx + ((size_t)b * E_ + i) * KNN_;
    float s = 0.f;
#pragma unroll
    for (int t = 0; t < KNN_; t++) s = __fadd_rn(s, xrow[id[t]]);
    float2 w; w.x = xrow[i]; w.y = s * (1.0f / 16.0f);
    *(float2*)&orow[2 * i] = w;
    qrow[i] = pk2bf(w.x, w.y);
  }
}

// ---------------------------------------------------------------------------
// cvt: ONE dispatch for all three fp32->bf16 conversions (verified r16).
// ---------------------------------------------------------------------------
__global__ __launch_bounds__(256) void k_cvt3(const float* __restrict__ xe,
                                              const float* __restrict__ wi,
                                              const float* __restrict__ wo,
                                              short* __restrict__ Xe,
                                              short* __restrict__ Wi,
                                              short* __restrict__ Wo) {
  const size_t t = (size_t)blockIdx.x * 256 + threadIdx.x;
  const float* src; short* dst;
  if (t < 1048576u) { src = xe + t * 8; dst = Xe + t * 8; }
  else if (t < 1048576u + 393216u) {
    const size_t r = t - 1048576u; src = wi + r * 8; dst = Wi + r * 8;
  } else {
    const size_t r = t - 1441792u; src = wo + r * 8; dst = Wo + r * 8;
  }
  float4 a = *(const float4*)src, b = *(const float4*)(src + 4);
  short8_t v;
  v[0] = f2bf(a.x); v[1] = f2bf(a.y); v[2] = f2bf(a.z); v[3] = f2bf(a.w);
  v[4] = f2bf(b.x); v[5] = f2bf(b.y); v[6] = f2bf(b.z); v[7] = f2bf(b.w);
  *(short8_t*)dst = v;
}

// ---------------------------------------------------------------------------
// K4a: merged Q/K/V projection, gload_lds staging (verified r14).
// ---------------------------------------------------------------------------
__global__ __launch_bounds__(256) void k_gemm_qkv(
    const short* __restrict__ Xq, const short* __restrict__ Xe,
    const short* __restrict__ Win, const float* __restrict__ b_in,
    short* __restrict__ Qb, short* __restrict__ Kb, short* __restrict__ Vb) {
  __shared__ __align__(16) short As[128 * 64];
  __shared__ __align__(16) short Bs[128 * 64];
  const int tid = threadIdx.x;
  const int z = blockIdx.z;
  const short* X = (z == 0) ? Xq : Xe;
  const short* W = Win + (size_t)z * EMB_ * EMB_;
  const float* bias = b_in + z * EMB_;
  const int row0 = blockIdx.x * 128, col0 = blockIdx.y * 128;
  const int l = tid & 63, lg = l >> 4, lq = l & 15;
  const int w = tid >> 6, wm = w >> 1, wn = w & 1;
  float4_t acc[4][4];
#pragma unroll
  for (int i = 0; i < 4; i++)
#pragma unroll
    for (int j = 0; j < 4; j++) {
      acc[i][j][0] = 0.f; acc[i][j][1] = 0.f; acc[i][j][2] = 0.f; acc[i][j][3] = 0.f;
    }

  int soff[4], ldsb[4];
#pragma unroll
  for (int ii = 0; ii < 4; ii++) {
    const int cid = ii * 256 + tid;
    const int r = cid >> 3, c = cid & 7;
    soff[ii] = r * EMB_ + ((c * 8) ^ ((r & 7) << 3));
    ldsb[ii] = (ii * 256 + w * 64) * 8;        // shorts (wave-uniform)
  }
  const short* Xb = X + (size_t)row0 * EMB_;
  const short* Wb = W + (size_t)col0 * EMB_;

  for (int kt = 0; kt < 16; kt++) {
    __syncthreads();
#pragma unroll
    for (int ii = 0; ii < 4; ii++) {
      gload16(Xb + soff[ii] + kt * 64, As + ldsb[ii]);
      gload16(Wb + soff[ii] + kt * 64, Bs + ldsb[ii]);
    }
    __syncthreads();
#pragma unroll
    for (int kk = 0; kk < 2; kk++) {
      short8_t af[4], bf[4];
#pragma unroll
      for (int mi = 0; mi < 4; mi++) {
        const int r = wm * 64 + mi * 16 + lq;
        af[mi] = *(const short8_t*)&As[r * 64 + ((kk * 32 + lg * 8) ^ ((r & 7) << 3))];
      }
#pragma unroll
      for (int ni = 0; ni < 4; ni++) {
        const int r = wn * 64 + ni * 16 + lq;
        bf[ni] = *(const short8_t*)&Bs[r * 64 + ((kk * 32 + lg * 8) ^ ((r & 7) << 3))];
      }
#pragma unroll
      for (int mi = 0; mi < 4; mi++)
#pragma unroll
        for (int ni = 0; ni < 4; ni++)
          acc[mi][ni] = __builtin_amdgcn_mfma_f32_16x16x32_bf16(af[mi], bf[ni], acc[mi][ni], 0, 0, 0);
    }
  }
  short* Yb = (z == 0) ? Qb : ((z == 1) ? Kb : Vb);
#pragma unroll
  for (int ni = 0; ni < 4; ni++) {
    const int col = col0 + wn * 64 + ni * 16 + lq;
    const float bv = bias[col];
#pragma unroll
    for (int mi = 0; mi < 4; mi++) {
#pragma unroll
      for (int j = 0; j < 4; j++) {
        const int m = row0 + wm * 64 + mi * 16 + lg * 4 + j;
        const float v = acc[mi][ni][j] + bv;
        if (z < 2) {
          Yb[(size_t)m * EMB_ + col] = f2bf(v);
        } else {
          const int b2 = m >> 11, n2 = m & (N_ - 1);
          Yb[((size_t)b2 * EMB_ + col) * N_ + n2] = f2bf(v);
        }
      }
    }
  }
}

// ---------------------------------------------------------------------------
// K4b: output projection (fp32 into out rows [N,2N)) — verified r11 body.
// ---------------------------------------------------------------------------
__global__ __launch_bounds__(256) void k_gemm_out(
    const short* __restrict__ X, const short* __restrict__ W,
    const float* __restrict__ bias, float* __restrict__ Yf) {
  __shared__ __align__(16) short As[128 * 64];
  __shared__ __align__(16) short Bs[128 * 64];
  const int tid = threadIdx.x;
  const int row0 = blockIdx.x * 128, col0 = blockIdx.y * 128;
  const int l = tid & 63, lg = l >> 4, lq = l & 15;
  const int w = tid >> 6, wm = w >> 1, wn = w & 1;
  float4_t acc[4][4];
#pragma unroll
  for (int i = 0; i < 4; i++)
#pragma unroll
    for (int j = 0; j < 4; j++) {
      acc[i][j][0] = 0.f; acc[i][j][1] = 0.f; acc[i][j][2] = 0.f; acc[i][j][3] = 0.f;
    }

  int soff[4], ldsb[4];
#pragma unroll
  for (int ii = 0; ii < 4; ii++) {
    const int cid = ii * 256 + tid;
    const int r = cid >> 3, c = cid & 7;
    soff[ii] = r * EMB_ + ((c * 8) ^ ((r & 7) << 3));
    ldsb[ii] = (ii * 256 + w * 64) * 8;
  }
  const short* Xb = X + (size_t)row0 * EMB_;
  const short* Wb = W + (size_t)col0 * EMB_;

  for (int kt = 0; kt < 16; kt++) {
    __syncthreads();
#pragma unroll
    for (int ii = 0; ii < 4; ii++) {
      gload16(Xb + soff[ii] + kt * 64, As + ldsb[ii]);
      gload16(Wb + soff[ii] + kt * 64, Bs + ldsb[ii]);
    }
    __syncthreads();
#pragma unroll
    for (int kk = 0; kk < 2; kk++) {
      short8_t af[4], bf[4];
#pragma unroll
      for (int mi = 0; mi < 4; mi++) {
        const int r = wm * 64 + mi * 16 + lq;
        af[mi] = *(const short8_t*)&As[r * 64 + ((kk * 32 + lg * 8) ^ ((r & 7) << 3))];
      }
#pragma unroll
      for (int ni = 0; ni < 4; ni++) {
        const int r = wn * 64 + ni * 16 + lq;
        bf[ni] = *(const short8_t*)&Bs[r * 64 + ((kk * 32 + lg * 8) ^ ((r & 7) << 3))];
      }
#pragma unroll
      for (int mi = 0; mi < 4; mi++)
#pragma unroll
        for (int ni = 0; ni < 4; ni++)
          acc[mi][ni] = __builtin_amdgcn_mfma_f32_16x16x32_bf16(af[mi], bf[ni], acc[mi][ni], 0, 0, 0);
    }
  }
#pragma unroll
  for (int ni = 0; ni < 4; ni++) {
    const int col = col0 + wn * 64 + ni * 16 + lq;
    const float bv = bias[col];
#pragma unroll
    for (int mi = 0; mi < 4; mi++) {
#pragma unroll
      for (int j = 0; j < 4; j++) {
        const int m = row0 + wm * 64 + mi * 16 + lg * 4 + j;
        const int b2 = m >> 11, n2 = m & (N_ - 1);
        Yf[((size_t)b2 * 2 * N_ + N_ + n2) * EMB_ + col] = acc[mi][ni][j] + bv;
      }
    }
  }
}

// ---------------------------------------------------------------------------
// K5 r19: SPLIT-KV flash. Each (bh, rt) Q-tile is covered by TWO blocks,
// each over half the key range (16 x 64-key tiles) -> grid 1024 = 4
// blocks/CU (was 2). Single-buffered 32KB LDS, gload_lds staging (GEMM-
// verified pattern), ~100 VGPR, launch_bounds(256,4) -> 4 waves/SIMD: one
// block's barrier stall is filled by another block's waves. Writes
// NORMALIZED partial O_h (bf16) + per-(row,head) (m_h, l_h); k_comb merges
// exactly: O = sum(w_h*O_h)/sum(w_h), w_h = l_h*2^((m_h-M)*c1).
// ---------------------------------------------------------------------------
__global__ __launch_bounds__(256, 4) void k_flash_split(
    const short* __restrict__ Qg, const short* __restrict__ Kg,
    const short* __restrict__ Vtg, short* __restrict__ O0,
    short* __restrict__ O1, float2* __restrict__ ml) {
  __shared__ __align__(16) short Ks[64 * 128];  // [key][d] 16-phase swz
  __shared__ __align__(16) short Vs[128 * 64];  // [d][key] 8-phase swz
  const int tid = threadIdx.x;
  const int w = tid >> 6, l = tid & 63;
  const int hi = l >> 5, l5 = l & 31;
  const int bid = blockIdx.x;                   // 1024 blocks
  const int r = bid >> 3;                       // 0..127
  const int half = r & 1;
  const int rt = (r >> 1) & 15;
  const int bh = (bid & 7) * 4 + (r >> 5);
  const int b = bh >> 3, h = bh & 7;
  const float c1 = 0.08838834764831845f * 1.4426950408889634f;  // scale*log2e
  const size_t bhoff = (size_t)b * N_ * EMB_ + (size_t)h * D_;
  const int ksw = (l5 & 15) << 3;   // Ks read swizzle (16-phase)
  const int psw = (l5 & 7) << 3;    // Vs read swizzle (8-phase)

  int ksrc[4], vsrc[4], ldb[4];
#pragma unroll
  for (int ii = 0; ii < 4; ii++) {
    const int cid = ii * 256 + tid;
    const int kr = cid >> 4, kc = cid & 15;
    const int vr = cid >> 3, vc = cid & 7;
    ksrc[ii] = kr * EMB_ + ((kc * 8) ^ ((kr & 15) << 3));
    vsrc[ii] = vr * N_ + ((vc * 8) ^ ((vr & 7) << 3));
    ldb[ii] = (ii * 256 + w * 64) * 8;       // shorts, wave-uniform
  }
  const short* Kt0 = Kg + bhoff + (size_t)(half * 1024) * EMB_;
  const short* Vt0 = Vtg + (size_t)b * EMB_ * N_ + (size_t)(h * D_) * N_
                     + half * 1024;

  short8_t qf[8];
  {
    const short* qrow = Qg + bhoff + (size_t)(rt * 128 + w * 32 + l5) * EMB_;
#pragma unroll
    for (int s = 0; s < 8; s++)
      qf[s] = *(const short8_t*)(qrow + s * 16 + hi * 8);
  }
  float16_t oacc[4];
#pragma unroll
  for (int dg = 0; dg < 4; dg++)
#pragma unroll
    for (int rr = 0; rr < 16; rr++) oacc[dg][rr] = 0.f;
  float m = -3.0e38f, lsum = 0.f;

  for (int t = 0; t < 16; t++) {
    __syncthreads();                     // prior tile's reads done
    const short* Kt = Kt0 + (size_t)(t * 64) * EMB_;
    const short* Vt = Vt0 + t * 64;
#pragma unroll
    for (int ii = 0; ii < 4; ii++) {
      gload16(Kt + ksrc[ii], Ks + ldb[ii]);
      gload16(Vt + vsrc[ii], Vs + ldb[ii]);
    }
    __syncthreads();                     // drains vmcnt -> data visible

    // ---- S^T = K . Q^T  (two 32-key groups, 8 k-slices each)
    float16_t s0, s1;
#pragma unroll
    for (int rr = 0; rr < 16; rr++) { s0[rr] = 0.f; s1[rr] = 0.f; }
    __builtin_amdgcn_s_setprio(1);
#pragma unroll
    for (int s = 0; s < 8; s++) {
      const int col = (s * 16 + hi * 8) ^ ksw;
      short8_t kf0 = *(const short8_t*)&Ks[l5 * 128 + col];
      short8_t kf1 = *(const short8_t*)&Ks[(32 + l5) * 128 + col];
      s0 = __builtin_amdgcn_mfma_f32_32x32x16_bf16(kf0, qf[s], s0, 0, 0, 0);
      s1 = __builtin_amdgcn_mfma_f32_32x32x16_bf16(kf1, qf[s], s1, 0, 0, 0);
    }
    __builtin_amdgcn_s_setprio(0);

    // ---- online softmax with defer-max; p = exp2(S*c1 - m*c1)
    float tm = s0[0];
#pragma unroll
    for (int rr = 1; rr < 16; rr++) tm = fmaxf(tm, s0[rr]);
#pragma unroll
    for (int rr = 0; rr < 16; rr++) tm = fmaxf(tm, s1[rr]);
    tm = fmaxf(tm, __shfl_xor(tm, 32));
    if (__any(tm > m + 62.7f)) {         // 62.7*c1 = 8 -> P <= 2^8
      const float mn = fmaxf(m, tm);
      const float alpha = fexp2((m - mn) * c1);
      m = mn;
      lsum *= alpha;
#pragma unroll
      for (int dg = 0; dg < 4; dg++)
#pragma unroll
        for (int rr = 0; rr < 16; rr++) oacc[dg][rr] *= alpha;
    }
    const float mc1 = m * c1;
    float ps = 0.f;
    unsigned w0[8], w1[8];               // w0[t]=keys(8t+4hi+0,1), w1[t]=(+2,3)
#pragma unroll
    for (int t2 = 0; t2 < 4; t2++) {
      float p0 = fexp2(__builtin_fmaf(s0[4 * t2 + 0], c1, -mc1));
      float p1 = fexp2(__builtin_fmaf(s0[4 * t2 + 1], c1, -mc1));
      float p2 = fexp2(__builtin_fmaf(s0[4 * t2 + 2], c1, -mc1));
      float p3 = fexp2(__builtin_fmaf(s0[4 * t2 + 3], c1, -mc1));
      ps += (p0 + p1) + (p2 + p3);
      w0[t2] = pk2bf(p0, p1); w1[t2] = pk2bf(p2, p3);
    }
#pragma unroll
    for (int t2 = 0; t2 < 4; t2++) {
      float p0 = fexp2(__builtin_fmaf(s1[4 * t2 + 0], c1, -mc1));
      float p1 = fexp2(__builtin_fmaf(s1[4 * t2 + 1], c1, -mc1));
      float p2 = fexp2(__builtin_fmaf(s1[4 * t2 + 2], c1, -mc1));
      float p3 = fexp2(__builtin_fmaf(s1[4 * t2 + 3], c1, -mc1));
      ps += (p0 + p1) + (p2 + p3);
      w0[4 + t2] = pk2bf(p0, p1); w1[4 + t2] = pk2bf(p2, p3);
    }
    ps += __shfl_xor(ps, 32);
    lsum += ps;

    // ---- build PV B-fragments in-register (T12): 2 permlane32_swap / group
    short8_t pf[4];
#pragma unroll
    for (int ks = 0; ks < 4; ks++) {
      const int t0 = 2 * ks, t1 = 2 * ks + 1;
      uint2_t ra = __builtin_amdgcn_permlane32_swap(w0[t0], w0[t1], false, false);
      uint2_t rb = __builtin_amdgcn_permlane32_swap(w1[t0], w1[t1], false, false);
      uint4_t pw; pw[0] = ra[0]; pw[1] = rb[0]; pw[2] = ra[1]; pw[3] = rb[1];
      pf[ks] = *(short8_t*)&pw;
    }

    // ---- O^T += V^T . P^T  (4 d-groups x 4 key-slices)
    __builtin_amdgcn_s_setprio(1);
#pragma unroll
    for (int ks = 0; ks < 4; ks++) {
      const int col = (ks * 16 + hi * 8) ^ psw;
#pragma unroll
      for (int dg = 0; dg < 4; dg++) {
        short8_t vf = *(const short8_t*)&Vs[(dg * 32 + l5) * 64 + col];
        oacc[dg] = __builtin_amdgcn_mfma_f32_32x32x16_bf16(vf, pf[ks], oacc[dg], 0, 0, 0);
      }
    }
    __builtin_amdgcn_s_setprio(0);
  }

  // ---- epilogue: normalized partial O + (m, l) per (row, head)
  const float linv = 1.0f / lsum;
  const int row = rt * 128 + w * 32 + l5;
  short* orow = (half ? O1 : O0) + bhoff + (size_t)row * EMB_;
#pragma unroll
  for (int dg = 0; dg < 4; dg++) {
#pragma unroll
    for (int g = 0; g < 4; g++) {
      float p0 = oacc[dg][4 * g + 0] * linv;
      float p1 = oacc[dg][4 * g + 1] * linv;
      float p2 = oacc[dg][4 * g + 2] * linv;
      float p3 = oacc[dg][4 * g + 3] * linv;
      uint2 ow; ow.x = pk2bf(p0, p1); ow.y = pk2bf(p2, p3);
      *(uint2*)&orow[dg * 32 + g * 8 + hi * 4] = ow;
    }
  }
  if (hi == 0) {
    float2 v; v.x = m; v.y = lsum;
    ml[(size_t)half * B_ * H_ * N_ + ((size_t)b * H_ + h) * N_ + row] = v;
  }
}

// ---------------------------------------------------------------------------
// K5b: exact split-softmax combine, in-place into O0.
// ---------------------------------------------------------------------------
__global__ __launch_bounds__(256) void k_comb(const float2* __restrict__ ml,
                                              short* __restrict__ O0,
                                              const short* __restrict__ O1) {
  const int n = blockIdx.x, b = blockIdx.y;
  const int t = threadIdx.x;
  const int e0 = t * 4, h = e0 >> 7;
  const float c1 = 0.08838834764831845f * 1.4426950408889634f;
  const size_t mlh = ((size_t)b * H_ + h) * N_ + n;
  const float2 v0 = ml[mlh];
  const float2 v1 = ml[(size_t)B_ * H_ * N_ + mlh];
  const float M = fmaxf(v0.x, v1.x);
  float w0 = v0.y * fexp2((v0.x - M) * c1);
  float w1 = v1.y * fexp2((v1.x - M) * c1);
  const float inv = 1.f / (w0 + w1);
  w0 *= inv; w1 *= inv;
  const size_t off = ((size_t)b * N_ + n) * EMB_ + e0;
  short4_t a = *(short4_t*)(O0 + off);
  short4_t c = *(const short4_t*)(O1 + off);
  float o0 = bf2f(a[0]) * w0 + bf2f(c[0]) * w1;
  float o1 = bf2f(a[1]) * w0 + bf2f(c[1]) * w1;
  float o2 = bf2f(a[2]) * w0 + bf2f(c[2]) * w1;
  float o3 = bf2f(a[3]) * w0 + bf2f(c[3]) * w1;
  uint2 ow; ow.x = pk2bf(o0, o1); ow.y = pk2bf(o2, o3);
  *(uint2*)(O0 + off) = ow;
}

// ---------------------------------------------------------------------------
extern "C" void kernel_launch(void* const* d_in, const int* in_sizes, int n_in,
                              void* d_out, int out_size, void* d_ws, size_t ws_size,
                              hipStream_t stream) {
  const float* x     = (const float*)d_in[0];
  const float* x_enc = (const float*)d_in[1];
  const float* w_in  = (const float*)d_in[2];
  const float* b_in  = (const float*)d_in[3];
  const float* w_out = (const float*)d_in[4];
  const float* b_out = (const float*)d_in[5];
  float* out = (float*)d_out;
  char* wsb = (char*)d_ws;

  const size_t oG    = 0;                               // gram; later: ml
  const size_t oSq   = oG + (size_t)B_ * E_ * E_ * 4;
  const size_t oPart = oSq + (size_t)B_ * E_ * 4;
  const size_t oIdx  = oPart + (size_t)B_ * E_ * 16 * 4;
  const size_t oXq   = (oIdx + (size_t)B_ * E_ * KNN_ * 4 + 255) & ~(size_t)255;
  const size_t sB    = (size_t)B_ * N_ * EMB_ * 2;
  const size_t oXe   = oXq + sB;                        // Xe; later: Opart1
  const size_t oWin  = oXe + sB;
  const size_t oWo   = oWin + 3ull * EMB_ * EMB_ * 2;
  const size_t oQ    = oWo + (size_t)EMB_ * EMB_ * 2;
  const size_t oK    = oQ + sB;
  const size_t oV    = oK + sB;

  float* g    = (float*)(wsb + oG);
  float* part = (float*)(wsb + oPart);
  int*   idx  = (int*)(wsb + oIdx);
  short* Xq   = (short*)(wsb + oXq);                    // later: Opart0
  short* Xe   = (short*)(wsb + oXe);                    // later: Opart1
  short* Win  = (short*)(wsb + oWin);
  short* Wo   = (short*)(wsb + oWo);
  short* Qb   = (short*)(wsb + oQ);
  short* Kb   = (short*)(wsb + oK);
  short* Vb   = (short*)(wsb + oV);
  float2* ml  = (float2*)(wsb + oG);                    // reuses gram slot

  // 1) kNN: gram (j-half) + sqnp_part fused; topk folds the sq tree
  k_gram_sqnp<<<dim3(400, B_), 64, 0, stream>>>(x, g, part);
  k_topk<<<dim3(B_ * E_), 64, 0, stream>>>(part, g, idx);
  k_knnmean<<<dim3(N_, B_), 256, 0, stream>>>(x, idx, out, Xq);

  // 2) all bf16 conversions in one dispatch (Xq fused into knnmean)
  k_cvt3<<<dim3(6144), 256, 0, stream>>>(x_enc, w_in, w_out, Xe, Win, Wo);

  // 3) Q/K/V projections in ONE dispatch (z selects); V written transposed
  k_gemm_qkv<<<dim3(64, 8, 3), 256, 0, stream>>>(Xq, Xe, Win, b_in, Qb, Kb, Vb);

  // 4) attention: split-KV flash (Xq/Xe slots are dead -> partial-O buffers;
  //    gram slot dead -> ml), then exact combine in-place into Xq slot
  k_flash_split<<<dim3(1024), 256, 0, stream>>>(Qb, Kb, Vb, Xq, Xe, ml);
  k_comb<<<dim3(N_, B_), 256, 0, stream>>>(ml, Xq, Xe);

  // 5) output projection (reads combined O in Xq slot) -> out rows [N, 2N)
  k_gemm_out<<<dim3(64, 8), 256, 0, stream>>>(Xq, Wo, b_out, out);
}

// Round 20
// 334.691 us; speedup vs baseline: 1.8303x; 1.8303x over previous
//
#include <hip/hip_runtime.h>
#include <hip/hip_bf16.h>

#define B_ 4
#define N_ 2048
#define E_ 512
#define EMB_ 1024
#define H_ 8
#define D_ 128
#define KNN_ 16

typedef short short8_t __attribute__((ext_vector_type(8)));
typedef short short4_t __attribute__((ext_vector_type(4)));
typedef float float2_t __attribute__((ext_vector_type(2)));
typedef float float4_t __attribute__((ext_vector_type(4)));
typedef float float16_t __attribute__((ext_vector_type(16)));
typedef unsigned int uint2_t __attribute__((ext_vector_type(2)));
typedef unsigned int uint4_t __attribute__((ext_vector_type(4)));

__device__ __forceinline__ short f2bf(float f) {
  unsigned u = __float_as_uint(f);
  unsigned r = u + 0x7fffu + ((u >> 16) & 1u);   // RNE to bf16
  return (short)(r >> 16);
}

__device__ __forceinline__ unsigned pk2bf(float a, float b) {
  float2 f; f.x = a; f.y = b;
  __hip_bfloat162 h = __float22bfloat162_rn(f);
  return *(unsigned*)&h;
}

__device__ __forceinline__ float bf2f(short s) {
  return __uint_as_float(((unsigned)(unsigned short)s) << 16);
}

__device__ __forceinline__ float fexp2(float x) {
  return __builtin_amdgcn_exp2f(x);
}

// async global->LDS, 16 B per lane (per-lane global addr, wave-linear LDS dest)
__device__ __forceinline__ void gload16(const short* g, short* l) {
  __builtin_amdgcn_global_load_lds(
      (const __attribute__((address_space(1))) void*)g,
      (__attribute__((address_space(3))) void*)l, 16, 0, 0);
}

// exact 16-value pairwise tree, bit-identical to the r7-verified k_sqnp_fin
__device__ __forceinline__ float tree16(const float* __restrict__ bs) {
  float t1[8], t2[4];
#pragma unroll
  for (int l = 0; l < 8; l++) t1[l] = __fadd_rn(bs[2 * l], bs[2 * l + 1]);
#pragma unroll
  for (int l = 0; l < 4; l++) t2[l] = __fadd_rn(t1[2 * l], t1[2 * l + 1]);
  return __fadd_rn(__fadd_rn(t2[0], t2[1]), __fadd_rn(t2[2], t2[3]));
}

// ---------------------------------------------------------------------------
// K1: Gram j-half split + fused sqnp_part (verified r16/r18). Bit-exact.
// ---------------------------------------------------------------------------
__global__ __launch_bounds__(64) void k_gram_sqnp(const float* __restrict__ x,
                                                  float* __restrict__ g,
                                                  float* __restrict__ part) {
  const int bx = blockIdx.x;
  const int b = blockIdx.y;
  if (bx >= 272) {                       // ---- sqnp_part path
    const int idx = (bx - 272) * 64 + threadIdx.x;   // 0..8191
    const int e = idx & (E_ - 1), blk = idx >> 9;
    const float* p = x + (size_t)b * N_ * E_ + (size_t)blk * 128 * E_ + e;
    float lane[16];
#pragma unroll
    for (int l = 0; l < 16; l++) {
      float pr[8];
#pragma unroll
      for (int j = 0; j < 8; j++) {
        float v = p[(size_t)(j * 16 + l) * E_];
        pr[j] = __fmul_rn(v, v);
      }
      float s01 = __fadd_rn(pr[0], pr[1]);
      float s23 = __fadd_rn(pr[2], pr[3]);
      float s45 = __fadd_rn(pr[4], pr[5]);
      float s67 = __fadd_rn(pr[6], pr[7]);
      lane[l] = __fadd_rn(__fadd_rn(s01, s23), __fadd_rn(s45, s67));
    }
    float bb[8];
#pragma unroll
    for (int l = 0; l < 8; l++) bb[l] = __fadd_rn(lane[l], lane[l + 8]);
    float cc[4];
#pragma unroll
    for (int l = 0; l < 4; l++) cc[l] = __fadd_rn(bb[l], bb[l + 4]);
    part[((size_t)b * E_ + e) * 16 + blk] =
        __fadd_rn(__fadd_rn(cc[0], cc[1]), __fadd_rn(cc[2], cc[3]));
    return;
  }
  // ---- gram path (verified r13/r16): 32i x 16j half-pair per wave
  __shared__ __align__(16) float Xs[2][32][68];  // [0..31]=i, [32..47]=j half
  int p = bx >> 1;
  const int jh = bx & 1;
  int ti = 0;
  while (p >= 16 - ti) { p -= 16 - ti; ti++; }
  const int tj = ti + p;
  const int i0 = ti * 32, j0 = tj * 32 + jh * 16;
  const int lane = threadIdx.x;
  const int li = lane & 7, lj = lane >> 3;     // compute: i-quad, j-pair
  const int cq = lane & 7, rn = lane >> 3;     // i-staging: ch-quad, n-row
  const int qj = lane & 3, rj = lane >> 2;     // j-staging: ch-quad, n-row
  const float* xb = x + (size_t)b * N_ * E_;

  float acc[4][2];
#pragma unroll
  for (int u = 0; u < 4; u++) { acc[u][0] = 0.f; acc[u][1] = 0.f; }

  float4_t gi[4], gj[2];
#pragma unroll
  for (int ps = 0; ps < 4; ps++) {       // chunk 0 i-part -> regs
    const int n = ps * 8 + rn;
    gi[ps] = *(const float4_t*)(xb + (size_t)n * E_ + i0 + cq * 4);
  }
#pragma unroll
  for (int s = 0; s < 2; s++) {          // chunk 0 j-part -> regs
    const int n = s * 16 + rj;
    gj[s] = *(const float4_t*)(xb + (size_t)n * E_ + j0 + qj * 4);
  }
#pragma unroll
  for (int ps = 0; ps < 4; ps++) {       // regs -> buf0 (i)
    const int nn = ps * 8 + rn;
    *(float4_t*)&Xs[0][nn][(cq * 4) ^ ((nn & 7) << 2)] = gi[ps];
  }
#pragma unroll
  for (int s = 0; s < 2; s++) {          // regs -> buf0 (j)
    const int nn = s * 16 + rj;
    *(float4_t*)&Xs[0][nn][32 + ((qj * 4) ^ ((nn & 3) << 2))] = gj[s];
  }

  for (int c = 0; c < 64; c++) {
    const int buf = c & 1;
    if (c < 63) {                        // issue next chunk's global loads
      const int nb = (c + 1) * 32;
#pragma unroll
      for (int ps = 0; ps < 4; ps++) {
        const int n = nb + ps * 8 + rn;
        gi[ps] = *(const float4_t*)(xb + (size_t)n * E_ + i0 + cq * 4);
      }
#pragma unroll
      for (int s = 0; s < 2; s++) {
        const int n = nb + s * 16 + rj;
        gj[s] = *(const float4_t*)(xb + (size_t)n * E_ + j0 + qj * 4);
      }
    }
#pragma unroll
    for (int nn = 0; nn < 32; nn++) {    // compute 32 nn (exact chain order)
      const float4_t va = *(const float4_t*)
          &Xs[buf][nn][(li * 4) ^ ((nn & 7) << 2)];
      const float2_t vb = *(const float2_t*)
          &Xs[buf][nn][32 + (((lj >> 1) * 4) ^ ((nn & 3) << 2)) + (lj & 1) * 2];
#pragma unroll
      for (int u = 0; u < 4; u++) {
        acc[u][0] = __fadd_rn(acc[u][0], __fmul_rn(va[u], vb[0]));
        acc[u][1] = __fadd_rn(acc[u][1], __fmul_rn(va[u], vb[1]));
      }
    }
    if (c < 63) {                        // regs -> other buffer (no barrier:
#pragma unroll
      for (int ps = 0; ps < 4; ps++) {   //  single wave, disjoint buffer)
        const int nn = ps * 8 + rn;
        *(float4_t*)&Xs[buf ^ 1][nn][(cq * 4) ^ ((nn & 7) << 2)] = gi[ps];
      }
#pragma unroll
      for (int s = 0; s < 2; s++) {
        const int nn = s * 16 + rj;
        *(float4_t*)&Xs[buf ^ 1][nn][32 + ((qj * 4) ^ ((nn & 3) << 2))] = gj[s];
      }
    }
  }
  float* gb = g + (size_t)b * E_ * E_;
#pragma unroll
  for (int u = 0; u < 4; u++) {
#pragma unroll
    for (int v = 0; v < 2; v++) {
      const int i = i0 + li * 4 + u, j = j0 + lj * 2 + v;
      gb[(size_t)i * E_ + j] = acc[u][v];
      if (ti != tj) gb[(size_t)j * E_ + i] = acc[u][v];
    }
  }
}

// ---------------------------------------------------------------------------
// K2: top-16 with inline sq tree (verified r16), single-wave butterfly.
// ---------------------------------------------------------------------------
__global__ __launch_bounds__(64) void k_topk(const float* __restrict__ part,
                                             const float* __restrict__ g,
                                             int* __restrict__ idxout) {
  const int bi = blockIdx.x;            // b*E + i
  const int b = bi >> 9, i = bi & (E_ - 1);
  const int lane = threadIdx.x;
  const float* gb = g + ((size_t)b * E_ + i) * E_;
  const float* pb = part + ((size_t)b << 9) * 16;
  const float sqi = tree16(pb + (size_t)i * 16);
  const int base = lane * 8;
  float v[8];
#pragma unroll
  for (int u = 0; u < 8; u++) {
    const float sqj = tree16(pb + (size_t)(base + u) * 16);
    v[u] = __fsub_rn(__fadd_rn(sqi, sqj), __fmul_rn(2.0f, gb[base + u]));
  }
  for (int t = 0; t < KNN_; t++) {
    float best = 3.0e38f; int bidx = E_;
#pragma unroll
    for (int u = 0; u < 8; u++) {
      if (v[u] < best) { best = v[u]; bidx = base + u; }
    }
#pragma unroll
    for (int off = 1; off < 64; off <<= 1) {
      float ov = __shfl_xor(best, off);
      int oi = __shfl_xor(bidx, off);
      if (ov < best || (ov == best && oi < bidx)) { best = ov; bidx = oi; }
    }
    if (lane == 0) idxout[(size_t)bi * KNN_ + t] = bidx;
#pragma unroll
    for (int u = 0; u < 8; u++) {
      if (bidx == base + u) v[u] = 3.0e38f;
    }
  }
}

// ---------------------------------------------------------------------------
// K3: x_knn mean + interleaved q + fused bf16 Xq write (verified r14).
// ---------------------------------------------------------------------------
__global__ __launch_bounds__(256) void k_knnmean(const float* __restrict__ x,
                                                 const int* __restrict__ idx,
                                                 float* __restrict__ out,
                                                 short* __restrict__ Xq) {
  const int n = blockIdx.x, b = blockIdx.y;
  const int tid = threadIdx.x;
  __shared__ float xrow[E_];
  const float* xr = x + ((size_t)b * N_ + n) * E_;
  for (int i = tid; i < E_; i += 256) xrow[i] = xr[i];
  __syncthreads();
  float* orow = out + ((size_t)b * (2 * N_) + n) * EMB_;
  unsigned* qrow = (unsigned*)(Xq + ((size_t)b * N_ + n) * EMB_);
  for (int i = tid; i < E_; i += 256) {
    const int* id = idx + ((size_t)b * E_ + i) * KNN_;
    float s = 0.f;
#pragma unroll
    for (int t = 0; t < KNN_; t++) s = __fadd_rn(s, xrow[id[t]]);
    float2 w; w.x = xrow[i]; w.y = s * (1.0f / 16.0f);
    *(float2*)&orow[2 * i] = w;
    qrow[i] = pk2bf(w.x, w.y);
  }
}

// ---------------------------------------------------------------------------
// cvt: ONE dispatch for all three fp32->bf16 conversions (verified r16).
// ---------------------------------------------------------------------------
__global__ __launch_bounds__(256) void k_cvt3(const float* __restrict__ xe,
                                              const float* __restrict__ wi,
                                              const float* __restrict__ wo,
                                              short* __restrict__ Xe,
                                              short* __restrict__ Wi,
                                              short* __restrict__ Wo) {
  const size_t t = (size_t)blockIdx.x * 256 + threadIdx.x;
  const float* src; short* dst;
  if (t < 1048576u) { src = xe + t * 8; dst = Xe + t * 8; }
  else if (t < 1048576u + 393216u) {
    const size_t r = t - 1048576u; src = wi + r * 8; dst = Wi + r * 8;
  } else {
    const size_t r = t - 1441792u; src = wo + r * 8; dst = Wo + r * 8;
  }
  float4 a = *(const float4*)src, b = *(const float4*)(src + 4);
  short8_t v;
  v[0] = f2bf(a.x); v[1] = f2bf(a.y); v[2] = f2bf(a.z); v[3] = f2bf(a.w);
  v[4] = f2bf(b.x); v[5] = f2bf(b.y); v[6] = f2bf(b.z); v[7] = f2bf(b.w);
  *(short8_t*)dst = v;
}

// ---------------------------------------------------------------------------
// K4a: merged Q/K/V projection, gload_lds staging (verified r14).
// ---------------------------------------------------------------------------
__global__ __launch_bounds__(256) void k_gemm_qkv(
    const short* __restrict__ Xq, const short* __restrict__ Xe,
    const short* __restrict__ Win, const float* __restrict__ b_in,
    short* __restrict__ Qb, short* __restrict__ Kb, short* __restrict__ Vb) {
  __shared__ __align__(16) short As[128 * 64];
  __shared__ __align__(16) short Bs[128 * 64];
  const int tid = threadIdx.x;
  const int z = blockIdx.z;
  const short* X = (z == 0) ? Xq : Xe;
  const short* W = Win + (size_t)z * EMB_ * EMB_;
  const float* bias = b_in + z * EMB_;
  const int row0 = blockIdx.x * 128, col0 = blockIdx.y * 128;
  const int l = tid & 63, lg = l >> 4, lq = l & 15;
  const int w = tid >> 6, wm = w >> 1, wn = w & 1;
  float4_t acc[4][4];
#pragma unroll
  for (int i = 0; i < 4; i++)
#pragma unroll
    for (int j = 0; j < 4; j++) {
      acc[i][j][0] = 0.f; acc[i][j][1] = 0.f; acc[i][j][2] = 0.f; acc[i][j][3] = 0.f;
    }

  int soff[4], ldsb[4];
#pragma unroll
  for (int ii = 0; ii < 4; ii++) {
    const int cid = ii * 256 + tid;
    const int r = cid >> 3, c = cid & 7;
    soff[ii] = r * EMB_ + ((c * 8) ^ ((r & 7) << 3));
    ldsb[ii] = (ii * 256 + w * 64) * 8;        // shorts (wave-uniform)
  }
  const short* Xb = X + (size_t)row0 * EMB_;
  const short* Wb = W + (size_t)col0 * EMB_;

  for (int kt = 0; kt < 16; kt++) {
    __syncthreads();
#pragma unroll
    for (int ii = 0; ii < 4; ii++) {
      gload16(Xb + soff[ii] + kt * 64, As + ldsb[ii]);
      gload16(Wb + soff[ii] + kt * 64, Bs + ldsb[ii]);
    }
    __syncthreads();
#pragma unroll
    for (int kk = 0; kk < 2; kk++) {
      short8_t af[4], bf[4];
#pragma unroll
      for (int mi = 0; mi < 4; mi++) {
        const int r = wm * 64 + mi * 16 + lq;
        af[mi] = *(const short8_t*)&As[r * 64 + ((kk * 32 + lg * 8) ^ ((r & 7) << 3))];
      }
#pragma unroll
      for (int ni = 0; ni < 4; ni++) {
        const int r = wn * 64 + ni * 16 + lq;
        bf[ni] = *(const short8_t*)&Bs[r * 64 + ((kk * 32 + lg * 8) ^ ((r & 7) << 3))];
      }
#pragma unroll
      for (int mi = 0; mi < 4; mi++)
#pragma unroll
        for (int ni = 0; ni < 4; ni++)
          acc[mi][ni] = __builtin_amdgcn_mfma_f32_16x16x32_bf16(af[mi], bf[ni], acc[mi][ni], 0, 0, 0);
    }
  }
  short* Yb = (z == 0) ? Qb : ((z == 1) ? Kb : Vb);
#pragma unroll
  for (int ni = 0; ni < 4; ni++) {
    const int col = col0 + wn * 64 + ni * 16 + lq;
    const float bv = bias[col];
#pragma unroll
    for (int mi = 0; mi < 4; mi++) {
#pragma unroll
      for (int j = 0; j < 4; j++) {
        const int m = row0 + wm * 64 + mi * 16 + lg * 4 + j;
        const float v = acc[mi][ni][j] + bv;
        if (z < 2) {
          Yb[(size_t)m * EMB_ + col] = f2bf(v);
        } else {
          const int b2 = m >> 11, n2 = m & (N_ - 1);
          Yb[((size_t)b2 * EMB_ + col) * N_ + n2] = f2bf(v);
        }
      }
    }
  }
}

// ---------------------------------------------------------------------------
// K4b: output projection (fp32 into out rows [N,2N)) — verified r11 body.
// ---------------------------------------------------------------------------
__global__ __launch_bounds__(256) void k_gemm_out(
    const short* __restrict__ X, const short* __restrict__ W,
    const float* __restrict__ bias, float* __restrict__ Yf) {
  __shared__ __align__(16) short As[128 * 64];
  __shared__ __align__(16) short Bs[128 * 64];
  const int tid = threadIdx.x;
  const int row0 = blockIdx.x * 128, col0 = blockIdx.y * 128;
  const int l = tid & 63, lg = l >> 4, lq = l & 15;
  const int w = tid >> 6, wm = w >> 1, wn = w & 1;
  float4_t acc[4][4];
#pragma unroll
  for (int i = 0; i < 4; i++)
#pragma unroll
    for (int j = 0; j < 4; j++) {
      acc[i][j][0] = 0.f; acc[i][j][1] = 0.f; acc[i][j][2] = 0.f; acc[i][j][3] = 0.f;
    }

  int soff[4], ldsb[4];
#pragma unroll
  for (int ii = 0; ii < 4; ii++) {
    const int cid = ii * 256 + tid;
    const int r = cid >> 3, c = cid & 7;
    soff[ii] = r * EMB_ + ((c * 8) ^ ((r & 7) << 3));
    ldsb[ii] = (ii * 256 + w * 64) * 8;
  }
  const short* Xb = X + (size_t)row0 * EMB_;
  const short* Wb = W + (size_t)col0 * EMB_;

  for (int kt = 0; kt < 16; kt++) {
    __syncthreads();
#pragma unroll
    for (int ii = 0; ii < 4; ii++) {
      gload16(Xb + soff[ii] + kt * 64, As + ldsb[ii]);
      gload16(Wb + soff[ii] + kt * 64, Bs + ldsb[ii]);
    }
    __syncthreads();
#pragma unroll
    for (int kk = 0; kk < 2; kk++) {
      short8_t af[4], bf[4];
#pragma unroll
      for (int mi = 0; mi < 4; mi++) {
        const int r = wm * 64 + mi * 16 + lq;
        af[mi] = *(const short8_t*)&As[r * 64 + ((kk * 32 + lg * 8) ^ ((r & 7) << 3))];
      }
#pragma unroll
      for (int ni = 0; ni < 4; ni++) {
        const int r = wn * 64 + ni * 16 + lq;
        bf[ni] = *(const short8_t*)&Bs[r * 64 + ((kk * 32 + lg * 8) ^ ((r & 7) << 3))];
      }
#pragma unroll
      for (int mi = 0; mi < 4; mi++)
#pragma unroll
        for (int ni = 0; ni < 4; ni++)
          acc[mi][ni] = __builtin_amdgcn_mfma_f32_16x16x32_bf16(af[mi], bf[ni], acc[mi][ni], 0, 0, 0);
    }
  }
#pragma unroll
  for (int ni = 0; ni < 4; ni++) {
    const int col = col0 + wn * 64 + ni * 16 + lq;
    const float bv = bias[col];
#pragma unroll
    for (int mi = 0; mi < 4; mi++) {
#pragma unroll
      for (int j = 0; j < 4; j++) {
        const int m = row0 + wm * 64 + mi * 16 + lg * 4 + j;
        const int b2 = m >> 11, n2 = m & (N_ - 1);
        Yf[((size_t)b2 * 2 * N_ + N_ + n2) * EMB_ + col] = acc[mi][ni][j] + bv;
      }
    }
  }
}

// ---------------------------------------------------------------------------
// K5 r20: SPLIT-KV flash (r19 body, correctness-verified) with
// __launch_bounds__(256, 2): r19's (256,4) capped VGPR at 64 and spilled
// ~1.6 GB to scratch (the 378µs regression). With the (256,2) cap the body
// compiles to ~100 VGPR (r18-measured); 32KB LDS + ~100 VGPR still admits
// 4 blocks/CU at runtime (LDS 128<=160KB, VGPR 16x100<=2048/SIMD).
// ---------------------------------------------------------------------------
__global__ __launch_bounds__(256, 2) void k_flash_split(
    const short* __restrict__ Qg, const short* __restrict__ Kg,
    const short* __restrict__ Vtg, short* __restrict__ O0,
    short* __restrict__ O1, float2* __restrict__ ml) {
  __shared__ __align__(16) short Ks[64 * 128];  // [key][d] 16-phase swz
  __shared__ __align__(16) short Vs[128 * 64];  // [d][key] 8-phase swz
  const int tid = threadIdx.x;
  const int w = tid >> 6, l = tid & 63;
  const int hi = l >> 5, l5 = l & 31;
  const int bid = blockIdx.x;                   // 1024 blocks
  const int r = bid >> 3;                       // 0..127
  const int half = r & 1;
  const int rt = (r >> 1) & 15;
  const int bh = (bid & 7) * 4 + (r >> 5);
  const int b = bh >> 3, h = bh & 7;
  const float c1 = 0.08838834764831845f * 1.4426950408889634f;  // scale*log2e
  const size_t bhoff = (size_t)b * N_ * EMB_ + (size_t)h * D_;
  const int ksw = (l5 & 15) << 3;   // Ks read swizzle (16-phase)
  const int psw = (l5 & 7) << 3;    // Vs read swizzle (8-phase)

  int ksrc[4], vsrc[4], ldb[4];
#pragma unroll
  for (int ii = 0; ii < 4; ii++) {
    const int cid = ii * 256 + tid;
    const int kr = cid >> 4, kc = cid & 15;
    const int vr = cid >> 3, vc = cid & 7;
    ksrc[ii] = kr * EMB_ + ((kc * 8) ^ ((kr & 15) << 3));
    vsrc[ii] = vr * N_ + ((vc * 8) ^ ((vr & 7) << 3));
    ldb[ii] = (ii * 256 + w * 64) * 8;       // shorts, wave-uniform
  }
  const short* Kt0 = Kg + bhoff + (size_t)(half * 1024) * EMB_;
  const short* Vt0 = Vtg + (size_t)b * EMB_ * N_ + (size_t)(h * D_) * N_
                     + half * 1024;

  short8_t qf[8];
  {
    const short* qrow = Qg + bhoff + (size_t)(rt * 128 + w * 32 + l5) * EMB_;
#pragma unroll
    for (int s = 0; s < 8; s++)
      qf[s] = *(const short8_t*)(qrow + s * 16 + hi * 8);
  }
  float16_t oacc[4];
#pragma unroll
  for (int dg = 0; dg < 4; dg++)
#pragma unroll
    for (int rr = 0; rr < 16; rr++) oacc[dg][rr] = 0.f;
  float m = -3.0e38f, lsum = 0.f;

  for (int t = 0; t < 16; t++) {
    __syncthreads();                     // prior tile's reads done
    const short* Kt = Kt0 + (size_t)(t * 64) * EMB_;
    const short* Vt = Vt0 + t * 64;
#pragma unroll
    for (int ii = 0; ii < 4; ii++) {
      gload16(Kt + ksrc[ii], Ks + ldb[ii]);
      gload16(Vt + vsrc[ii], Vs + ldb[ii]);
    }
    __syncthreads();                     // drains vmcnt -> data visible

    // ---- S^T = K . Q^T  (two 32-key groups, 8 k-slices each)
    float16_t s0, s1;
#pragma unroll
    for (int rr = 0; rr < 16; rr++) { s0[rr] = 0.f; s1[rr] = 0.f; }
    __builtin_amdgcn_s_setprio(1);
#pragma unroll
    for (int s = 0; s < 8; s++) {
      const int col = (s * 16 + hi * 8) ^ ksw;
      short8_t kf0 = *(const short8_t*)&Ks[l5 * 128 + col];
      short8_t kf1 = *(const short8_t*)&Ks[(32 + l5) * 128 + col];
      s0 = __builtin_amdgcn_mfma_f32_32x32x16_bf16(kf0, qf[s], s0, 0, 0, 0);
      s1 = __builtin_amdgcn_mfma_f32_32x32x16_bf16(kf1, qf[s], s1, 0, 0, 0);
    }
    __builtin_amdgcn_s_setprio(0);

    // ---- online softmax with defer-max; p = exp2(S*c1 - m*c1)
    float tm = s0[0];
#pragma unroll
    for (int rr = 1; rr < 16; rr++) tm = fmaxf(tm, s0[rr]);
#pragma unroll
    for (int rr = 0; rr < 16; rr++) tm = fmaxf(tm, s1[rr]);
    tm = fmaxf(tm, __shfl_xor(tm, 32));
    if (__any(tm > m + 62.7f)) {         // 62.7*c1 = 8 -> P <= 2^8
      const float mn = fmaxf(m, tm);
      const float alpha = fexp2((m - mn) * c1);
      m = mn;
      lsum *= alpha;
#pragma unroll
      for (int dg = 0; dg < 4; dg++)
#pragma unroll
        for (int rr = 0; rr < 16; rr++) oacc[dg][rr] *= alpha;
    }
    const float mc1 = m * c1;
    float ps = 0.f;
    unsigned w0[8], w1[8];               // w0[t]=keys(8t+4hi+0,1), w1[t]=(+2,3)
#pragma unroll
    for (int t2 = 0; t2 < 4; t2++) {
      float p0 = fexp2(__builtin_fmaf(s0[4 * t2 + 0], c1, -mc1));
      float p1 = fexp2(__builtin_fmaf(s0[4 * t2 + 1], c1, -mc1));
      float p2 = fexp2(__builtin_fmaf(s0[4 * t2 + 2], c1, -mc1));
      float p3 = fexp2(__builtin_fmaf(s0[4 * t2 + 3], c1, -mc1));
      ps += (p0 + p1) + (p2 + p3);
      w0[t2] = pk2bf(p0, p1); w1[t2] = pk2bf(p2, p3);
    }
#pragma unroll
    for (int t2 = 0; t2 < 4; t2++) {
      float p0 = fexp2(__builtin_fmaf(s1[4 * t2 + 0], c1, -mc1));
      float p1 = fexp2(__builtin_fmaf(s1[4 * t2 + 1], c1, -mc1));
      float p2 = fexp2(__builtin_fmaf(s1[4 * t2 + 2], c1, -mc1));
      float p3 = fexp2(__builtin_fmaf(s1[4 * t2 + 3], c1, -mc1));
      ps += (p0 + p1) + (p2 + p3);
      w0[4 + t2] = pk2bf(p0, p1); w1[4 + t2] = pk2bf(p2, p3);
    }
    ps += __shfl_xor(ps, 32);
    lsum += ps;

    // ---- build PV B-fragments in-register (T12): 2 permlane32_swap / group
    short8_t pf[4];
#pragma unroll
    for (int ks = 0; ks < 4; ks++) {
      const int t0 = 2 * ks, t1 = 2 * ks + 1;
      uint2_t ra = __builtin_amdgcn_permlane32_swap(w0[t0], w0[t1], false, false);
      uint2_t rb = __builtin_amdgcn_permlane32_swap(w1[t0], w1[t1], false, false);
      uint4_t pw; pw[0] = ra[0]; pw[1] = rb[0]; pw[2] = ra[1]; pw[3] = rb[1];
      pf[ks] = *(short8_t*)&pw;
    }

    // ---- O^T += V^T . P^T  (4 d-groups x 4 key-slices)
    __builtin_amdgcn_s_setprio(1);
#pragma unroll
    for (int ks = 0; ks < 4; ks++) {
      const int col = (ks * 16 + hi * 8) ^ psw;
#pragma unroll
      for (int dg = 0; dg < 4; dg++) {
        short8_t vf = *(const short8_t*)&Vs[(dg * 32 + l5) * 64 + col];
        oacc[dg] = __builtin_amdgcn_mfma_f32_32x32x16_bf16(vf, pf[ks], oacc[dg], 0, 0, 0);
      }
    }
    __builtin_amdgcn_s_setprio(0);
  }

  // ---- epilogue: normalized partial O + (m, l) per (row, head)
  const float linv = 1.0f / lsum;
  const int row = rt * 128 + w * 32 + l5;
  short* orow = (half ? O1 : O0) + bhoff + (size_t)row * EMB_;
#pragma unroll
  for (int dg = 0; dg < 4; dg++) {
#pragma unroll
    for (int g = 0; g < 4; g++) {
      float p0 = oacc[dg][4 * g + 0] * linv;
      float p1 = oacc[dg][4 * g + 1] * linv;
      float p2 = oacc[dg][4 * g + 2] * linv;
      float p3 = oacc[dg][4 * g + 3] * linv;
      uint2 ow; ow.x = pk2bf(p0, p1); ow.y = pk2bf(p2, p3);
      *(uint2*)&orow[dg * 32 + g * 8 + hi * 4] = ow;
    }
  }
  if (hi == 0) {
    float2 v; v.x = m; v.y = lsum;
    ml[(size_t)half * B_ * H_ * N_ + ((size_t)b * H_ + h) * N_ + row] = v;
  }
}

// ---------------------------------------------------------------------------
// K5b: exact split-softmax combine, in-place into O0 (verified r19).
// ---------------------------------------------------------------------------
__global__ __launch_bounds__(256) void k_comb(const float2* __restrict__ ml,
                                              short* __restrict__ O0,
                                              const short* __restrict__ O1) {
  const int n = blockIdx.x, b = blockIdx.y;
  const int t = threadIdx.x;
  const int e0 = t * 4, h = e0 >> 7;
  const float c1 = 0.08838834764831845f * 1.4426950408889634f;
  const size_t mlh = ((size_t)b * H_ + h) * N_ + n;
  const float2 v0 = ml[mlh];
  const float2 v1 = ml[(size_t)B_ * H_ * N_ + mlh];
  const float M = fmaxf(v0.x, v1.x);
  float w0 = v0.y * fexp2((v0.x - M) * c1);
  float w1 = v1.y * fexp2((v1.x - M) * c1);
  const float inv = 1.f / (w0 + w1);
  w0 *= inv; w1 *= inv;
  const size_t off = ((size_t)b * N_ + n) * EMB_ + e0;
  short4_t a = *(short4_t*)(O0 + off);
  short4_t c = *(const short4_t*)(O1 + off);
  float o0 = bf2f(a[0]) * w0 + bf2f(c[0]) * w1;
  float o1 = bf2f(a[1]) * w0 + bf2f(c[1]) * w1;
  float o2 = bf2f(a[2]) * w0 + bf2f(c[2]) * w1;
  float o3 = bf2f(a[3]) * w0 + bf2f(c[3]) * w1;
  uint2 ow; ow.x = pk2bf(o0, o1); ow.y = pk2bf(o2, o3);
  *(uint2*)(O0 + off) = ow;
}

// ---------------------------------------------------------------------------
extern "C" void kernel_launch(void* const* d_in, const int* in_sizes, int n_in,
                              void* d_out, int out_size, void* d_ws, size_t ws_size,
                              hipStream_t stream) {
  const float* x     = (const float*)d_in[0];
  const float* x_enc = (const float*)d_in[1];
  const float* w_in  = (const float*)d_in[2];
  const float* b_in  = (const float*)d_in[3];
  const float* w_out = (const float*)d_in[4];
  const float* b_out = (const float*)d_in[5];
  float* out = (float*)d_out;
  char* wsb = (char*)d_ws;

  const size_t oG    = 0;                               // gram; later: ml
  const size_t oSq   = oG + (size_t)B_ * E_ * E_ * 4;
  const size_t oPart = oSq + (size_t)B_ * E_ * 4;
  const size_t oIdx  = oPart + (size_t)B_ * E_ * 16 * 4;
  const size_t oXq   = (oIdx + (size_t)B_ * E_ * KNN_ * 4 + 255) & ~(size_t)255;
  const size_t sB    = (size_t)B_ * N_ * EMB_ * 2;
  const size_t oXe   = oXq + sB;                        // Xe; later: Opart1
  const size_t oWin  = oXe + sB;
  const size_t oWo   = oWin + 3ull * EMB_ * EMB_ * 2;
  const size_t oQ    = oWo + (size_t)EMB_ * EMB_ * 2;
  const size_t oK    = oQ + sB;
  const size_t oV    = oK + sB;

  float* g    = (float*)(wsb + oG);
  float* part = (float*)(wsb + oPart);
  int*   idx  = (int*)(wsb + oIdx);
  short* Xq   = (short*)(wsb + oXq);                    // later: Opart0
  short* Xe   = (short*)(wsb + oXe);                    // later: Opart1
  short* Win  = (short*)(wsb + oWin);
  short* Wo   = (short*)(wsb + oWo);
  short* Qb   = (short*)(wsb + oQ);
  short* Kb   = (short*)(wsb + oK);
  short* Vb   = (short*)(wsb + oV);
  float2* ml  = (float2*)(wsb + oG);                    // reuses gram slot

  // 1) kNN: gram (j-half) + sqnp_part fused; topk folds the sq tree
  k_gram_sqnp<<<dim3(400, B_), 64, 0, stream>>>(x, g, part);
  k_topk<<<dim3(B_ * E_), 64, 0, stream>>>(part, g, idx);
  k_knnmean<<<dim3(N_, B_), 256, 0, stream>>>(x, idx, out, Xq);

  // 2) all bf16 conversions in one dispatch (Xq fused into knnmean)
  k_cvt3<<<dim3(6144), 256, 0, stream>>>(x_enc, w_in, w_out, Xe, Win, Wo);

  // 3) Q/K/V projections in ONE dispatch (z selects); V written transposed
  k_gemm_qkv<<<dim3(64, 8, 3), 256, 0, stream>>>(Xq, Xe, Win, b_in, Qb, Kb, Vb);

  // 4) attention: split-KV flash (Xq/Xe slots are dead -> partial-O buffers;
  //    gram slot dead -> ml), then exact combine in-place into Xq slot
  k_flash_split<<<dim3(1024), 256, 0, stream>>>(Qb, Kb, Vb, Xq, Xe, ml);
  k_comb<<<dim3(N_, B_), 256, 0, stream>>>(ml, Xq, Xe);

  // 5) output projection (reads combined O in Xq slot) -> out rows [N, 2N)
  k_gemm_out<<<dim3(64, 8), 256, 0, stream>>>(Xq, Wo, b_out, out);
}

// Round 21
// 319.949 us; speedup vs baseline: 1.9146x; 1.0461x over previous
//
#include <hip/hip_runtime.h>
#include <hip/hip_bf16.h>

#define B_ 4
#define N_ 2048
#define E_ 512
#define EMB_ 1024
#define H_ 8
#define D_ 128
#define KNN_ 16

typedef short short8_t __attribute__((ext_vector_type(8)));
typedef short short4_t __attribute__((ext_vector_type(4)));
typedef float float2_t __attribute__((ext_vector_type(2)));
typedef float float4_t __attribute__((ext_vector_type(4)));
typedef float float16_t __attribute__((ext_vector_type(16)));
typedef unsigned int uint2_t __attribute__((ext_vector_type(2)));
typedef unsigned int uint4_t __attribute__((ext_vector_type(4)));

__device__ __forceinline__ short f2bf(float f) {
  unsigned u = __float_as_uint(f);
  unsigned r = u + 0x7fffu + ((u >> 16) & 1u);   // RNE to bf16
  return (short)(r >> 16);
}

__device__ __forceinline__ unsigned pk2bf(float a, float b) {
  float2 f; f.x = a; f.y = b;
  __hip_bfloat162 h = __float22bfloat162_rn(f);
  return *(unsigned*)&h;
}

__device__ __forceinline__ float fexp2(float x) {
  return __builtin_amdgcn_exp2f(x);
}

// async global->LDS, 16 B per lane (per-lane global addr, wave-linear LDS dest)
__device__ __forceinline__ void gload16(const short* g, short* l) {
  __builtin_amdgcn_global_load_lds(
      (const __attribute__((address_space(1))) void*)g,
      (__attribute__((address_space(3))) void*)l, 16, 0, 0);
}

// exact 16-value pairwise tree, bit-identical to the r7-verified k_sqnp_fin
__device__ __forceinline__ float tree16(const float* __restrict__ bs) {
  float t1[8], t2[4];
#pragma unroll
  for (int l = 0; l < 8; l++) t1[l] = __fadd_rn(bs[2 * l], bs[2 * l + 1]);
#pragma unroll
  for (int l = 0; l < 4; l++) t2[l] = __fadd_rn(t1[2 * l], t1[2 * l + 1]);
  return __fadd_rn(__fadd_rn(t2[0], t2[1]), __fadd_rn(t2[2], t2[3]));
}

// ---------------------------------------------------------------------------
// K1: Gram j-half split + fused sqnp_part (verified r16/r18). Bit-exact.
// ---------------------------------------------------------------------------
__global__ __launch_bounds__(64) void k_gram_sqnp(const float* __restrict__ x,
                                                  float* __restrict__ g,
                                                  float* __restrict__ part) {
  const int bx = blockIdx.x;
  const int b = blockIdx.y;
  if (bx >= 272) {                       // ---- sqnp_part path
    const int idx = (bx - 272) * 64 + threadIdx.x;   // 0..8191
    const int e = idx & (E_ - 1), blk = idx >> 9;
    const float* p = x + (size_t)b * N_ * E_ + (size_t)blk * 128 * E_ + e;
    float lane[16];
#pragma unroll
    for (int l = 0; l < 16; l++) {
      float pr[8];
#pragma unroll
      for (int j = 0; j < 8; j++) {
        float v = p[(size_t)(j * 16 + l) * E_];
        pr[j] = __fmul_rn(v, v);
      }
      float s01 = __fadd_rn(pr[0], pr[1]);
      float s23 = __fadd_rn(pr[2], pr[3]);
      float s45 = __fadd_rn(pr[4], pr[5]);
      float s67 = __fadd_rn(pr[6], pr[7]);
      lane[l] = __fadd_rn(__fadd_rn(s01, s23), __fadd_rn(s45, s67));
    }
    float bb[8];
#pragma unroll
    for (int l = 0; l < 8; l++) bb[l] = __fadd_rn(lane[l], lane[l + 8]);
    float cc[4];
#pragma unroll
    for (int l = 0; l < 4; l++) cc[l] = __fadd_rn(bb[l], bb[l + 4]);
    part[((size_t)b * E_ + e) * 16 + blk] =
        __fadd_rn(__fadd_rn(cc[0], cc[1]), __fadd_rn(cc[2], cc[3]));
    return;
  }
  // ---- gram path (verified r13/r16): 32i x 16j half-pair per wave
  __shared__ __align__(16) float Xs[2][32][68];  // [0..31]=i, [32..47]=j half
  int p = bx >> 1;
  const int jh = bx & 1;
  int ti = 0;
  while (p >= 16 - ti) { p -= 16 - ti; ti++; }
  const int tj = ti + p;
  const int i0 = ti * 32, j0 = tj * 32 + jh * 16;
  const int lane = threadIdx.x;
  const int li = lane & 7, lj = lane >> 3;     // compute: i-quad, j-pair
  const int cq = lane & 7, rn = lane >> 3;     // i-staging: ch-quad, n-row
  const int qj = lane & 3, rj = lane >> 2;     // j-staging: ch-quad, n-row
  const float* xb = x + (size_t)b * N_ * E_;

  float acc[4][2];
#pragma unroll
  for (int u = 0; u < 4; u++) { acc[u][0] = 0.f; acc[u][1] = 0.f; }

  float4_t gi[4], gj[2];
#pragma unroll
  for (int ps = 0; ps < 4; ps++) {       // chunk 0 i-part -> regs
    const int n = ps * 8 + rn;
    gi[ps] = *(const float4_t*)(xb + (size_t)n * E_ + i0 + cq * 4);
  }
#pragma unroll
  for (int s = 0; s < 2; s++) {          // chunk 0 j-part -> regs
    const int n = s * 16 + rj;
    gj[s] = *(const float4_t*)(xb + (size_t)n * E_ + j0 + qj * 4);
  }
#pragma unroll
  for (int ps = 0; ps < 4; ps++) {       // regs -> buf0 (i)
    const int nn = ps * 8 + rn;
    *(float4_t*)&Xs[0][nn][(cq * 4) ^ ((nn & 7) << 2)] = gi[ps];
  }
#pragma unroll
  for (int s = 0; s < 2; s++) {          // regs -> buf0 (j)
    const int nn = s * 16 + rj;
    *(float4_t*)&Xs[0][nn][32 + ((qj * 4) ^ ((nn & 3) << 2))] = gj[s];
  }

  for (int c = 0; c < 64; c++) {
    const int buf = c & 1;
    if (c < 63) {                        // issue next chunk's global loads
      const int nb = (c + 1) * 32;
#pragma unroll
      for (int ps = 0; ps < 4; ps++) {
        const int n = nb + ps * 8 + rn;
        gi[ps] = *(const float4_t*)(xb + (size_t)n * E_ + i0 + cq * 4);
      }
#pragma unroll
      for (int s = 0; s < 2; s++) {
        const int n = nb + s * 16 + rj;
        gj[s] = *(const float4_t*)(xb + (size_t)n * E_ + j0 + qj * 4);
      }
    }
#pragma unroll
    for (int nn = 0; nn < 32; nn++) {    // compute 32 nn (exact chain order)
      const float4_t va = *(const float4_t*)
          &Xs[buf][nn][(li * 4) ^ ((nn & 7) << 2)];
      const float2_t vb = *(const float2_t*)
          &Xs[buf][nn][32 + (((lj >> 1) * 4) ^ ((nn & 3) << 2)) + (lj & 1) * 2];
#pragma unroll
      for (int u = 0; u < 4; u++) {
        acc[u][0] = __fadd_rn(acc[u][0], __fmul_rn(va[u], vb[0]));
        acc[u][1] = __fadd_rn(acc[u][1], __fmul_rn(va[u], vb[1]));
      }
    }
    if (c < 63) {                        // regs -> other buffer (no barrier:
#pragma unroll
      for (int ps = 0; ps < 4; ps++) {   //  single wave, disjoint buffer)
        const int nn = ps * 8 + rn;
        *(float4_t*)&Xs[buf ^ 1][nn][(cq * 4) ^ ((nn & 7) << 2)] = gi[ps];
      }
#pragma unroll
      for (int s = 0; s < 2; s++) {
        const int nn = s * 16 + rj;
        *(float4_t*)&Xs[buf ^ 1][nn][32 + ((qj * 4) ^ ((nn & 3) << 2))] = gj[s];
      }
    }
  }
  float* gb = g + (size_t)b * E_ * E_;
#pragma unroll
  for (int u = 0; u < 4; u++) {
#pragma unroll
    for (int v = 0; v < 2; v++) {
      const int i = i0 + li * 4 + u, j = j0 + lj * 2 + v;
      gb[(size_t)i * E_ + j] = acc[u][v];
      if (ti != tj) gb[(size_t)j * E_ + i] = acc[u][v];
    }
  }
}

// ---------------------------------------------------------------------------
// K2: top-16 with inline sq tree (verified r16), single-wave butterfly.
// ---------------------------------------------------------------------------
__global__ __launch_bounds__(64) void k_topk(const float* __restrict__ part,
                                             const float* __restrict__ g,
                                             int* __restrict__ idxout) {
  const int bi = blockIdx.x;            // b*E + i
  const int b = bi >> 9, i = bi & (E_ - 1);
  const int lane = threadIdx.x;
  const float* gb = g + ((size_t)b * E_ + i) * E_;
  const float* pb = part + ((size_t)b << 9) * 16;
  const float sqi = tree16(pb + (size_t)i * 16);
  const int base = lane * 8;
  float v[8];
#pragma unroll
  for (int u = 0; u < 8; u++) {
    const float sqj = tree16(pb + (size_t)(base + u) * 16);
    v[u] = __fsub_rn(__fadd_rn(sqi, sqj), __fmul_rn(2.0f, gb[base + u]));
  }
  for (int t = 0; t < KNN_; t++) {
    float best = 3.0e38f; int bidx = E_;
#pragma unroll
    for (int u = 0; u < 8; u++) {
      if (v[u] < best) { best = v[u]; bidx = base + u; }
    }
#pragma unroll
    for (int off = 1; off < 64; off <<= 1) {
      float ov = __shfl_xor(best, off);
      int oi = __shfl_xor(bidx, off);
      if (ov < best || (ov == best && oi < bidx)) { best = ov; bidx = oi; }
    }
    if (lane == 0) idxout[(size_t)bi * KNN_ + t] = bidx;
#pragma unroll
    for (int u = 0; u < 8; u++) {
      if (bidx == base + u) v[u] = 3.0e38f;
    }
  }
}

// ---------------------------------------------------------------------------
// K3: x_knn mean + interleaved q + fused bf16 Xq write (verified r14).
// ---------------------------------------------------------------------------
__global__ __launch_bounds__(256) void k_knnmean(const float* __restrict__ x,
                                                 const int* __restrict__ idx,
                                                 float* __restrict__ out,
                                                 short* __restrict__ Xq) {
  const int n = blockIdx.x, b = blockIdx.y;
  const int tid = threadIdx.x;
  __shared__ float xrow[E_];
  const float* xr = x + ((size_t)b * N_ + n) * E_;
  for (int i = tid; i < E_; i += 256) xrow[i] = xr[i];
  __syncthreads();
  float* orow = out + ((size_t)b * (2 * N_) + n) * EMB_;
  unsigned* qrow = (unsigned*)(Xq + ((size_t)b * N_ + n) * EMB_);
  for (int i = tid; i < E_; i += 256) {
    const int* id = idx + ((size_t)b * E_ + i) * KNN_;
    float s = 0.f;
#pragma unroll
    for (int t = 0; t < KNN_; t++) s = __fadd_rn(s, xrow[id[t]]);
    float2 w; w.x = xrow[i]; w.y = s * (1.0f / 16.0f);
    *(float2*)&orow[2 * i] = w;
    qrow[i] = pk2bf(w.x, w.y);
  }
}

// ---------------------------------------------------------------------------
// cvt: ONE dispatch for all three fp32->bf16 conversions (verified r16).
// ---------------------------------------------------------------------------
__global__ __launch_bounds__(256) void k_cvt3(const float* __restrict__ xe,
                                              const float* __restrict__ wi,
                                              const float* __restrict__ wo,
                                              short* __restrict__ Xe,
                                              short* __restrict__ Wi,
                                              short* __restrict__ Wo) {
  const size_t t = (size_t)blockIdx.x * 256 + threadIdx.x;
  const float* src; short* dst;
  if (t < 1048576u) { src = xe + t * 8; dst = Xe + t * 8; }
  else if (t < 1048576u + 393216u) {
    const size_t r = t - 1048576u; src = wi + r * 8; dst = Wi + r * 8;
  } else {
    const size_t r = t - 1441792u; src = wo + r * 8; dst = Wo + r * 8;
  }
  float4 a = *(const float4*)src, b = *(const float4*)(src + 4);
  short8_t v;
  v[0] = f2bf(a.x); v[1] = f2bf(a.y); v[2] = f2bf(a.z); v[3] = f2bf(a.w);
  v[4] = f2bf(b.x); v[5] = f2bf(b.y); v[6] = f2bf(b.z); v[7] = f2bf(b.w);
  *(short8_t*)dst = v;
}

// ---------------------------------------------------------------------------
// K4a: merged Q/K/V projection, gload_lds staging (verified r14).
// ---------------------------------------------------------------------------
__global__ __launch_bounds__(256) void k_gemm_qkv(
    const short* __restrict__ Xq, const short* __restrict__ Xe,
    const short* __restrict__ Win, const float* __restrict__ b_in,
    short* __restrict__ Qb, short* __restrict__ Kb, short* __restrict__ Vb) {
  __shared__ __align__(16) short As[128 * 64];
  __shared__ __align__(16) short Bs[128 * 64];
  const int tid = threadIdx.x;
  const int z = blockIdx.z;
  const short* X = (z == 0) ? Xq : Xe;
  const short* W = Win + (size_t)z * EMB_ * EMB_;
  const float* bias = b_in + z * EMB_;
  const int row0 = blockIdx.x * 128, col0 = blockIdx.y * 128;
  const int l = tid & 63, lg = l >> 4, lq = l & 15;
  const int w = tid >> 6, wm = w >> 1, wn = w & 1;
  float4_t acc[4][4];
#pragma unroll
  for (int i = 0; i < 4; i++)
#pragma unroll
    for (int j = 0; j < 4; j++) {
      acc[i][j][0] = 0.f; acc[i][j][1] = 0.f; acc[i][j][2] = 0.f; acc[i][j][3] = 0.f;
    }

  int soff[4], ldsb[4];
#pragma unroll
  for (int ii = 0; ii < 4; ii++) {
    const int cid = ii * 256 + tid;
    const int r = cid >> 3, c = cid & 7;
    soff[ii] = r * EMB_ + ((c * 8) ^ ((r & 7) << 3));
    ldsb[ii] = (ii * 256 + w * 64) * 8;        // shorts (wave-uniform)
  }
  const short* Xb = X + (size_t)row0 * EMB_;
  const short* Wb = W + (size_t)col0 * EMB_;

  for (int kt = 0; kt < 16; kt++) {
    __syncthreads();
#pragma unroll
    for (int ii = 0; ii < 4; ii++) {
      gload16(Xb + soff[ii] + kt * 64, As + ldsb[ii]);
      gload16(Wb + soff[ii] + kt * 64, Bs + ldsb[ii]);
    }
    __syncthreads();
#pragma unroll
    for (int kk = 0; kk < 2; kk++) {
      short8_t af[4], bf[4];
#pragma unroll
      for (int mi = 0; mi < 4; mi++) {
        const int r = wm * 64 + mi * 16 + lq;
        af[mi] = *(const short8_t*)&As[r * 64 + ((kk * 32 + lg * 8) ^ ((r & 7) << 3))];
      }
#pragma unroll
      for (int ni = 0; ni < 4; ni++) {
        const int r = wn * 64 + ni * 16 + lq;
        bf[ni] = *(const short8_t*)&Bs[r * 64 + ((kk * 32 + lg * 8) ^ ((r & 7) << 3))];
      }
#pragma unroll
      for (int mi = 0; mi < 4; mi++)
#pragma unroll
        for (int ni = 0; ni < 4; ni++)
          acc[mi][ni] = __builtin_amdgcn_mfma_f32_16x16x32_bf16(af[mi], bf[ni], acc[mi][ni], 0, 0, 0);
    }
  }
  short* Yb = (z == 0) ? Qb : ((z == 1) ? Kb : Vb);
#pragma unroll
  for (int ni = 0; ni < 4; ni++) {
    const int col = col0 + wn * 64 + ni * 16 + lq;
    const float bv = bias[col];
#pragma unroll
    for (int mi = 0; mi < 4; mi++) {
#pragma unroll
      for (int j = 0; j < 4; j++) {
        const int m = row0 + wm * 64 + mi * 16 + lg * 4 + j;
        const float v = acc[mi][ni][j] + bv;
        if (z < 2) {
          Yb[(size_t)m * EMB_ + col] = f2bf(v);
        } else {
          const int b2 = m >> 11, n2 = m & (N_ - 1);
          Yb[((size_t)b2 * EMB_ + col) * N_ + n2] = f2bf(v);
        }
      }
    }
  }
}

// ---------------------------------------------------------------------------
// K4b: output projection (fp32 into out rows [N,2N)) — verified r11 body.
// ---------------------------------------------------------------------------
__global__ __launch_bounds__(256) void k_gemm_out(
    const short* __restrict__ X, const short* __restrict__ W,
    const float* __restrict__ bias, float* __restrict__ Yf) {
  __shared__ __align__(16) short As[128 * 64];
  __shared__ __align__(16) short Bs[128 * 64];
  const int tid = threadIdx.x;
  const int row0 = blockIdx.x * 128, col0 = blockIdx.y * 128;
  const int l = tid & 63, lg = l >> 4, lq = l & 15;
  const int w = tid >> 6, wm = w >> 1, wn = w & 1;
  float4_t acc[4][4];
#pragma unroll
  for (int i = 0; i < 4; i++)
#pragma unroll
    for (int j = 0; j < 4; j++) {
      acc[i][j][0] = 0.f; acc[i][j][1] = 0.f; acc[i][j][2] = 0.f; acc[i][j][3] = 0.f;
    }

  int soff[4], ldsb[4];
#pragma unroll
  for (int ii = 0; ii < 4; ii++) {
    const int cid = ii * 256 + tid;
    const int r = cid >> 3, c = cid & 7;
    soff[ii] = r * EMB_ + ((c * 8) ^ ((r & 7) << 3));
    ldsb[ii] = (ii * 256 + w * 64) * 8;
  }
  const short* Xb = X + (size_t)row0 * EMB_;
  const short* Wb = W + (size_t)col0 * EMB_;

  for (int kt = 0; kt < 16; kt++) {
    __syncthreads();
#pragma unroll
    for (int ii = 0; ii < 4; ii++) {
      gload16(Xb + soff[ii] + kt * 64, As + ldsb[ii]);
      gload16(Wb + soff[ii] + kt * 64, Bs + ldsb[ii]);
    }
    __syncthreads();
#pragma unroll
    for (int kk = 0; kk < 2; kk++) {
      short8_t af[4], bf[4];
#pragma unroll
      for (int mi = 0; mi < 4; mi++) {
        const int r = wm * 64 + mi * 16 + lq;
        af[mi] = *(const short8_t*)&As[r * 64 + ((kk * 32 + lg * 8) ^ ((r & 7) << 3))];
      }
#pragma unroll
      for (int ni = 0; ni < 4; ni++) {
        const int r = wn * 64 + ni * 16 + lq;
        bf[ni] = *(const short8_t*)&Bs[r * 64 + ((kk * 32 + lg * 8) ^ ((r & 7) << 3))];
      }
#pragma unroll
      for (int mi = 0; mi < 4; mi++)
#pragma unroll
        for (int ni = 0; ni < 4; ni++)
          acc[mi][ni] = __builtin_amdgcn_mfma_f32_16x16x32_bf16(af[mi], bf[ni], acc[mi][ni], 0, 0, 0);
    }
  }
#pragma unroll
  for (int ni = 0; ni < 4; ni++) {
    const int col = col0 + wn * 64 + ni * 16 + lq;
    const float bv = bias[col];
#pragma unroll
    for (int mi = 0; mi < 4; mi++) {
#pragma unroll
      for (int j = 0; j < 4; j++) {
        const int m = row0 + wm * 64 + mi * 16 + lg * 4 + j;
        const int b2 = m >> 11, n2 = m & (N_ - 1);
        Yf[((size_t)b2 * 2 * N_ + N_ + n2) * EMB_ + col] = acc[mi][ni][j] + bv;
      }
    }
  }
}

// ---------------------------------------------------------------------------
// K5: 32x32x16 flash, dbuf gload_lds staging, in-reg P (EXACT r15/r18 body —
// the best-measured 93µs version; split-KV r19/r20 reverted: no occupancy
// gain materialized and the combine pass added overhead).
// ---------------------------------------------------------------------------
__global__ __launch_bounds__(256, 2) void k_flash_bf16(
    const short* __restrict__ Qg, const short* __restrict__ Kg,
    const short* __restrict__ Vtg, short* __restrict__ Og) {
  __shared__ __align__(16) short Ks[2][64 * 128];  // [key][d] 16-phase swz
  __shared__ __align__(16) short Vs[2][128 * 64];  // [d][key] 8-phase swz
  const int tid = threadIdx.x;
  const int w = tid >> 6, l = tid & 63;
  const int hi = l >> 5, l5 = l & 31;
  const int bid = blockIdx.x;
  const int bh = (bid & 7) * 4 + ((bid >> 3) >> 4);
  const int rt = (bid >> 3) & 15;
  const int b = bh >> 3, h = bh & 7;
  const float c1 = 0.08838834764831845f * 1.4426950408889634f;  // scale*log2e
  const size_t bhoff = (size_t)b * N_ * EMB_ + (size_t)h * D_;
  const int ksw = (l5 & 15) << 3;   // Ks read swizzle (16-phase)
  const int psw = (l5 & 7) << 3;    // Vs read swizzle (8-phase)

  int ksrc[4], vsrc[4], ldb[4];
#pragma unroll
  for (int ii = 0; ii < 4; ii++) {
    const int cid = ii * 256 + tid;
    const int kr = cid >> 4, kc = cid & 15;
    const int vr = cid >> 3, vc = cid & 7;
    ksrc[ii] = kr * EMB_ + ((kc * 8) ^ ((kr & 15) << 3));
    vsrc[ii] = vr * N_ + ((vc * 8) ^ ((vr & 7) << 3));
    ldb[ii] = (ii * 256 + w * 64) * 8;       // shorts, wave-uniform
  }
  const short* Kt0 = Kg + bhoff;
  const short* Vt0 = Vtg + (size_t)b * EMB_ * N_ + (size_t)(h * D_) * N_;

  short8_t qf[8];
  {
    const short* qrow = Qg + bhoff + (size_t)(rt * 128 + w * 32 + l5) * EMB_;
#pragma unroll
    for (int s = 0; s < 8; s++)
      qf[s] = *(const short8_t*)(qrow + s * 16 + hi * 8);
  }
  float16_t oacc[4];
#pragma unroll
  for (int dg = 0; dg < 4; dg++)
#pragma unroll
    for (int r = 0; r < 16; r++) oacc[dg][r] = 0.f;
  float m = -3.0e38f, lsum = 0.f;

  // prologue: stage tile 0 into buf 0
#pragma unroll
  for (int ii = 0; ii < 4; ii++) {
    gload16(Kt0 + ksrc[ii], &Ks[0][ldb[ii]]);
    gload16(Vt0 + vsrc[ii], &Vs[0][ldb[ii]]);
  }
  __syncthreads();

  for (int kt = 0; kt < N_ / 64; kt++) {
    const int buf = kt & 1;
    if (kt + 1 < N_ / 64) {              // prefetch next tile into buf^1
      const short* Kt = Kt0 + (size_t)((kt + 1) * 64) * EMB_;
      const short* Vt = Vt0 + (kt + 1) * 64;
#pragma unroll
      for (int ii = 0; ii < 4; ii++) {
        gload16(Kt + ksrc[ii], &Ks[buf ^ 1][ldb[ii]]);
        gload16(Vt + vsrc[ii], &Vs[buf ^ 1][ldb[ii]]);
      }
    }

    // ---- S^T = K . Q^T  (two 32-key groups, 8 k-slices each)
    float16_t s0, s1;
#pragma unroll
    for (int r = 0; r < 16; r++) { s0[r] = 0.f; s1[r] = 0.f; }
    __builtin_amdgcn_s_setprio(1);
#pragma unroll
    for (int s = 0; s < 8; s++) {
      const int col = (s * 16 + hi * 8) ^ ksw;
      short8_t kf0 = *(const short8_t*)&Ks[buf][l5 * 128 + col];
      short8_t kf1 = *(const short8_t*)&Ks[buf][(32 + l5) * 128 + col];
      s0 = __builtin_amdgcn_mfma_f32_32x32x16_bf16(kf0, qf[s], s0, 0, 0, 0);
      s1 = __builtin_amdgcn_mfma_f32_32x32x16_bf16(kf1, qf[s], s1, 0, 0, 0);
    }
    __builtin_amdgcn_s_setprio(0);

    // ---- online softmax with defer-max; p = exp2(S*c1 - m*c1)
    float tm = s0[0];
#pragma unroll
    for (int r = 1; r < 16; r++) tm = fmaxf(tm, s0[r]);
#pragma unroll
    for (int r = 0; r < 16; r++) tm = fmaxf(tm, s1[r]);
    tm = fmaxf(tm, __shfl_xor(tm, 32));
    if (__any(tm > m + 62.7f)) {         // 62.7*c1 = 8 -> P <= 2^8
      const float mn = fmaxf(m, tm);
      const float alpha = fexp2((m - mn) * c1);
      m = mn;
      lsum *= alpha;
#pragma unroll
      for (int dg = 0; dg < 4; dg++)
#pragma unroll
        for (int r = 0; r < 16; r++) oacc[dg][r] *= alpha;
    }
    const float mc1 = m * c1;
    float ps = 0.f;
    unsigned w0[8], w1[8];               // w0[t]=keys(8t+4hi+0,1), w1[t]=(+2,3)
#pragma unroll
    for (int t = 0; t < 4; t++) {
      float p0 = fexp2(__builtin_fmaf(s0[4 * t + 0], c1, -mc1));
      float p1 = fexp2(__builtin_fmaf(s0[4 * t + 1], c1, -mc1));
      float p2 = fexp2(__builtin_fmaf(s0[4 * t + 2], c1, -mc1));
      float p3 = fexp2(__builtin_fmaf(s0[4 * t + 3], c1, -mc1));
      ps += (p0 + p1) + (p2 + p3);
      w0[t] = pk2bf(p0, p1); w1[t] = pk2bf(p2, p3);
    }
#pragma unroll
    for (int t = 0; t < 4; t++) {
      float p0 = fexp2(__builtin_fmaf(s1[4 * t + 0], c1, -mc1));
      float p1 = fexp2(__builtin_fmaf(s1[4 * t + 1], c1, -mc1));
      float p2 = fexp2(__builtin_fmaf(s1[4 * t + 2], c1, -mc1));
      float p3 = fexp2(__builtin_fmaf(s1[4 * t + 3], c1, -mc1));
      ps += (p0 + p1) + (p2 + p3);
      w0[4 + t] = pk2bf(p0, p1); w1[4 + t] = pk2bf(p2, p3);
    }
    ps += __shfl_xor(ps, 32);
    lsum += ps;

    // ---- build PV B-fragments in-register (T12): 2 permlane32_swap / group
    short8_t pf[4];
#pragma unroll
    for (int ks = 0; ks < 4; ks++) {
      const int t0 = 2 * ks, t1 = 2 * ks + 1;
      uint2_t ra = __builtin_amdgcn_permlane32_swap(w0[t0], w0[t1], false, false);
      uint2_t rb = __builtin_amdgcn_permlane32_swap(w1[t0], w1[t1], false, false);
      uint4_t pw; pw[0] = ra[0]; pw[1] = rb[0]; pw[2] = ra[1]; pw[3] = rb[1];
      pf[ks] = *(short8_t*)&pw;
    }

    // ---- O^T += V^T . P^T  (4 d-groups x 4 key-slices)
    __builtin_amdgcn_s_setprio(1);
#pragma unroll
    for (int ks = 0; ks < 4; ks++) {
      const int col = (ks * 16 + hi * 8) ^ psw;
#pragma unroll
      for (int dg = 0; dg < 4; dg++) {
        short8_t vf = *(const short8_t*)&Vs[buf][(dg * 32 + l5) * 64 + col];
        oacc[dg] = __builtin_amdgcn_mfma_f32_32x32x16_bf16(vf, pf[ks], oacc[dg], 0, 0, 0);
      }
    }
    __builtin_amdgcn_s_setprio(0);

    __syncthreads();   // drains this wave's gloads (vmcnt0) + joins waves
  }

  // ---- epilogue: O[q][d], d = dg*32 + 8g + 4hi + {0..3}, q = l5 (lane-local)
  const float linv = 1.0f / lsum;
  short* orow = Og + bhoff + (size_t)(rt * 128 + w * 32 + l5) * EMB_;
#pragma unroll
  for (int dg = 0; dg < 4; dg++) {
#pragma unroll
    for (int g = 0; g < 4; g++) {
      float p0 = oacc[dg][4 * g + 0] * linv;
      float p1 = oacc[dg][4 * g + 1] * linv;
      float p2 = oacc[dg][4 * g + 2] * linv;
      float p3 = oacc[dg][4 * g + 3] * linv;
      uint2 ow; ow.x = pk2bf(p0, p1); ow.y = pk2bf(p2, p3);
      *(uint2*)&orow[dg * 32 + g * 8 + hi * 4] = ow;
    }
  }
}

// ---------------------------------------------------------------------------
extern "C" void kernel_launch(void* const* d_in, const int* in_sizes, int n_in,
                              void* d_out, int out_size, void* d_ws, size_t ws_size,
                              hipStream_t stream) {
  const float* x     = (const float*)d_in[0];
  const float* x_enc = (const float*)d_in[1];
  const float* w_in  = (const float*)d_in[2];
  const float* b_in  = (const float*)d_in[3];
  const float* w_out = (const float*)d_in[4];
  const float* b_out = (const float*)d_in[5];
  float* out = (float*)d_out;
  char* wsb = (char*)d_ws;

  const size_t oG    = 0;
  const size_t oSq   = oG + (size_t)B_ * E_ * E_ * 4;   // (unused slot kept)
  const size_t oPart = oSq + (size_t)B_ * E_ * 4;
  const size_t oIdx  = oPart + (size_t)B_ * E_ * 16 * 4;
  const size_t oXq   = (oIdx + (size_t)B_ * E_ * KNN_ * 4 + 255) & ~(size_t)255;
  const size_t sB    = (size_t)B_ * N_ * EMB_ * 2;
  const size_t oXe   = oXq + sB;
  const size_t oWin  = oXe + sB;
  const size_t oWo   = oWin + 3ull * EMB_ * EMB_ * 2;
  const size_t oQ    = oWo + (size_t)EMB_ * EMB_ * 2;
  const size_t oK    = oQ + sB;
  const size_t oV    = oK + sB;
  const size_t oO    = oV + sB;
  const size_t need  = oO + sB;

  float* g    = (float*)(wsb + oG);
  float* part = (float*)(wsb + oPart);
  int*   idx  = (int*)(wsb + oIdx);
  short* Xq   = (short*)(wsb + oXq);
  short* Xe   = (short*)(wsb + oXe);
  short* Win  = (short*)(wsb + oWin);
  short* Wo   = (short*)(wsb + oWo);
  short* Qb   = (short*)(wsb + oQ);
  short* Kb   = (short*)(wsb + oK);
  short* Vb   = (short*)(wsb + oV);
  short* Ob   = (ws_size >= need) ? (short*)(wsb + oO) : Qb;

  // 1) kNN: gram (j-half) + sqnp_part fused; topk folds the sq tree
  k_gram_sqnp<<<dim3(400, B_), 64, 0, stream>>>(x, g, part);
  k_topk<<<dim3(B_ * E_), 64, 0, stream>>>(part, g, idx);
  k_knnmean<<<dim3(N_, B_), 256, 0, stream>>>(x, idx, out, Xq);

  // 2) all bf16 conversions in one dispatch (Xq fused into knnmean)
  k_cvt3<<<dim3(6144), 256, 0, stream>>>(x_enc, w_in, w_out, Xe, Win, Wo);

  // 3) Q/K/V projections in ONE dispatch (z selects); V written transposed
  k_gemm_qkv<<<dim3(64, 8, 3), 256, 0, stream>>>(Xq, Xe, Win, b_in, Qb, Kb, Vb);

  // 4) attention (bf16 MFMA flash, 32x32x16, dbuf gload_lds, in-reg P)
  k_flash_bf16<<<dim3(512), 256, 0, stream>>>(Qb, Kb, Vb, Ob);

  // 5) output projection -> fp32 into out rows [N, 2N)
  k_gemm_out<<<dim3(64, 8), 256, 0, stream>>>(Ob, Wo, b_out, out);
}